// Round 12
// baseline (287.232 us; speedup 1.0000x reference)
//
#include <hip/hip_runtime.h>

typedef unsigned short u16;
typedef unsigned int u32;
typedef __bf16 bf16x8 __attribute__((ext_vector_type(8)));
typedef float f32x4 __attribute__((ext_vector_type(4)));

// round-to-nearest-even f32 -> bf16 bits
__device__ __forceinline__ u16 f2bf(float f) {
  u32 u = __builtin_bit_cast(u32, f);
  u += 0x7fffu + ((u >> 16) & 1u);
  return (u16)(u >> 16);
}

#define GLOAD_LDS16(g, l) __builtin_amdgcn_global_load_lds( \
    (const __attribute__((address_space(1))) void*)(g),     \
    (__attribute__((address_space(3))) void*)(l), 16, 0, 0)

// scale folded into k-projection: C^-0.5 * log2(e)
#define SCK (0.03125f * 1.44269504088896f)

#define BARF() do { asm volatile("" ::: "memory"); \
                    __builtin_amdgcn_s_barrier();  \
                    asm volatile("" ::: "memory"); } while (0)

// ---------------------------------------------------------------------------
// Merged prep: blocks [0,4096): x f32->bf16; blocks [4096,5120): W transpose.
__global__ __launch_bounds__(256) void prep_k(const float* __restrict__ x,
                                              const float* __restrict__ W0,
                                              const float* __restrict__ W1,
                                              const float* __restrict__ W2,
                                              const float* __restrict__ W3,
                                              u16* __restrict__ xb,
                                              u16* __restrict__ WT) {
  __shared__ float tile[64][65];
  const int tid = threadIdx.x;
  if (blockIdx.x < 4096) {
    size_t i = (size_t)blockIdx.x * 256 + tid;
    const float4* p = reinterpret_cast<const float4*>(x) + i * 2;
    float4 a = p[0], b = p[1];
    u32 w0 = f2bf(a.x) | ((u32)f2bf(a.y) << 16);
    u32 w1 = f2bf(a.z) | ((u32)f2bf(a.w) << 16);
    u32 w2 = f2bf(b.x) | ((u32)f2bf(b.y) << 16);
    u32 w3 = f2bf(b.z) | ((u32)f2bf(b.w) << 16);
    uint4 o; o.x = w0; o.y = w1; o.z = w2; o.w = w3;
    *reinterpret_cast<uint4*>(xb + i * 8) = o;
    return;
  }
  const int bid2 = blockIdx.x - 4096;
  const int z = bid2 >> 8, kt = bid2 & 15, nt = (bid2 >> 4) & 15;
  const float* W = z == 0 ? W0 : z == 1 ? W1 : z == 2 ? W2 : W3;
  u16* dst = WT + (size_t)z * 1024 * 1024;
  const int k0 = kt * 64, n0 = nt * 64;
  const int rr = tid >> 4, c4 = (tid & 15) * 4;
#pragma unroll
  for (int p = 0; p < 4; ++p) {
    int r = rr + p * 16;
    float4 v = *reinterpret_cast<const float4*>(W + (size_t)(k0 + r) * 1024 + n0 + c4);
    tile[r][c4 + 0] = v.x; tile[r][c4 + 1] = v.y;
    tile[r][c4 + 2] = v.z; tile[r][c4 + 3] = v.w;
  }
  __syncthreads();
#pragma unroll
  for (int p = 0; p < 4; ++p) {
    int nl = rr + p * 16;
    u32 w0 = f2bf(tile[c4 + 0][nl]) | ((u32)f2bf(tile[c4 + 1][nl]) << 16);
    u32 w1 = f2bf(tile[c4 + 2][nl]) | ((u32)f2bf(tile[c4 + 3][nl]) << 16);
    uint2 o; o.x = w0; o.y = w1;
    *reinterpret_cast<uint2*>(dst + (size_t)(n0 + nl) * 1024 + k0 + c4) = o;
  }
}

// ---------------------------------------------------------------------------
// QKV bf16 GEMM, SINGLE-barrier K-loop (r11, unchanged).
template <int MODE>
__global__ __launch_bounds__(512, 2) void gemm8_k(
    const u16* __restrict__ A, const u16* __restrict__ BT,
    const float* __restrict__ bias0, const float* __restrict__ bias1,
    const float* __restrict__ bias2,
    u16* __restrict__ out_k, u16* __restrict__ out_q, u16* __restrict__ out_vT,
    float* __restrict__ out_f) {
  constexpr int BN = (MODE == 0) ? 192 : 128;
  constexpr int NB = BN / 64;        // col frags per wave: 3 or 2
  constexpr int LPT = 4 + NB;        // loads per thread per K-tile: 7 or 6
  constexpr int WCW = BN / 4;        // wave col width: 48 or 32
  constexpr int HALF = 8 + NB;       // reads per kk-half: 11 or 10

  __shared__ __align__(16) u16 As[2][256 * 64];
  __shared__ __align__(16) u16 Bs[2][BN * 64];

  const int tid = threadIdx.x;
  const int w = tid >> 6, lane = tid & 63;
  const int wr = w >> 2, wc = w & 3;
  const int fr = lane & 15, fq = lane >> 4;
  const int d = fr & 7;

  // XCD 2D region blocking (bijective; by varies fastest -> A-panel reuse)
  const int bid = (int)blockIdx.x;
  const int xcd = bid & 7, c = bid >> 3;
  int bx, by;
  if constexpr (MODE == 0) {
    bx = (xcd & 3) * 8 + (c >> 3);   // 4 bx-regions of 8
    by = (xcd >> 2) * 8 + (c & 7);   // 2 by-regions of 8
  } else {
    bx = xcd * 4 + (c >> 3);         // 8 bx-regions of 4
    by = c & 7;                      // all 8 by
  }
  const int row0 = bx * 256, col0 = by * BN;

  // staging source (inverse-swizzled per-lane global address)
  const int r0 = tid >> 3;
  const int cbg = (tid & 7) ^ (r0 & 7);
  const u16* Asrc = A + (size_t)(row0 + r0) * 1024 + cbg * 8;
  const u16* Bsrc = BT + (size_t)(col0 + r0) * 1024 + cbg * 8;

#define STAGE8(buf, t) do {                                                  \
    _Pragma("unroll")                                                        \
    for (int sw = 0; sw < 4; ++sw)                                           \
      GLOAD_LDS16(Asrc + (size_t)sw * 65536 + (t) * 64,                      \
                  &As[buf][sw * 4096 + tid * 8]);                            \
    _Pragma("unroll")                                                        \
    for (int sw = 0; sw < NB; ++sw)                                          \
      GLOAD_LDS16(Bsrc + (size_t)sw * 65536 + (t) * 64,                      \
                  &Bs[buf][sw * 4096 + tid * 8]);                            \
  } while (0)

  // swizzled frag byte offset: row*128 + (((kk*4+fq) ^ (row&7)) * 16)
#define AOFF(mb, kk) ((wr * 128 + (mb) * 16 + fr) * 128 + (((((kk) << 2) | fq) ^ d) << 4))
#define BOFF(nb, kk) ((wc * WCW + (nb) * 16 + fr) * 128 + (((((kk) << 2) | fq) ^ d) << 4))

  f32x4 acc[8][NB] = {};

  STAGE8(0, 0);
  STAGE8(1, 1);
  asm volatile("s_waitcnt vmcnt(%0)" :: "n"(LPT) : "memory");
  BARF();

#pragma unroll 1
  for (int g = 0; g < 16; ++g) {
    const int buf = g & 1;
    const char* Ac = (const char*)&As[buf][0];
    const char* Bc = (const char*)&Bs[buf][0];
    bf16x8 a[8][2], b[NB][2];

    // ---- issue ALL fragment reads: kk0 set first, then kk1 set ----
#pragma unroll
    for (int mb = 0; mb < 8; ++mb) a[mb][0] = *(const bf16x8*)(Ac + AOFF(mb, 0));
#pragma unroll
    for (int nb = 0; nb < NB; ++nb) b[nb][0] = *(const bf16x8*)(Bc + BOFF(nb, 0));
#pragma unroll
    for (int mb = 0; mb < 8; ++mb) a[mb][1] = *(const bf16x8*)(Ac + AOFF(mb, 1));
#pragma unroll
    for (int nb = 0; nb < NB; ++nb) b[nb][1] = *(const bf16x8*)(Bc + BOFF(nb, 1));

    // ---- kk0 MFMA burst; kk1 reads retire underneath ----
    asm volatile("s_waitcnt lgkmcnt(%0)" :: "n"(HALF) : "memory");
    __builtin_amdgcn_s_setprio(1);
#pragma unroll
    for (int mb = 0; mb < 8; ++mb)
#pragma unroll
      for (int nb = 0; nb < NB; ++nb)
        acc[mb][nb] = __builtin_amdgcn_mfma_f32_16x16x32_bf16(
            a[mb][0], b[nb][0], acc[mb][nb], 0, 0, 0);
    __builtin_amdgcn_s_setprio(0);

    // ---- ONE barrier merges both sync conditions ----
    asm volatile("s_waitcnt lgkmcnt(0)" ::: "memory");
    asm volatile("s_waitcnt vmcnt(0)" ::: "memory");
    BARF();
    if (g + 2 < 16) STAGE8(buf, g + 2);

    // ---- kk1 MFMA burst from registers (covers DMA issue) ----
    __builtin_amdgcn_s_setprio(1);
#pragma unroll
    for (int mb = 0; mb < 8; ++mb)
#pragma unroll
      for (int nb = 0; nb < NB; ++nb)
        acc[mb][nb] = __builtin_amdgcn_mfma_f32_16x16x32_bf16(
            a[mb][1], b[nb][1], acc[mb][nb], 0, 0, 0);
    __builtin_amdgcn_s_setprio(0);
  }
#undef STAGE8
#undef AOFF
#undef BOFF

  // ---- epilogue ----
  if constexpr (MODE == 0) {
#pragma unroll
    for (int mb = 0; mb < 8; ++mb) {
#pragma unroll
      for (int nb = 0; nb < NB; ++nb) {
        const int rg = row0 + wr * 128 + mb * 16 + fq * 4;
        const int cg = col0 + wc * WCW + nb * 16 + fr;
        const int which = cg >> 10;
        const int nloc = cg & 1023;
        const float bv = (which == 0 ? bias0 : which == 1 ? bias1 : bias2)[nloc];
        if (which == 0) {
#pragma unroll
          for (int r = 0; r < 4; ++r)
            out_k[(size_t)(rg + r) * 1024 + nloc] = f2bf((acc[mb][nb][r] + bv) * SCK);
        } else if (which == 1) {
#pragma unroll
          for (int r = 0; r < 4; ++r)
            out_q[(size_t)(rg + r) * 1024 + nloc] = f2bf(acc[mb][nb][r] + bv);
        } else {
          const int bb = rg >> 10, t = rg & 1023;
          const int hh = nloc >> 6, dl = nloc & 63;
          u32 w0 = f2bf(acc[mb][nb][0] + bv) | ((u32)f2bf(acc[mb][nb][1] + bv) << 16);
          u32 w1 = f2bf(acc[mb][nb][2] + bv) | ((u32)f2bf(acc[mb][nb][3] + bv) << 16);
          uint2 ov; ov.x = w0; ov.y = w1;
          *reinterpret_cast<uint2*>(out_vT + ((size_t)(bb * 16 + hh) * 64 + dl) * 1024 + t) = ov;
        }
      }
    }
  } else {
#pragma unroll
    for (int mb = 0; mb < 8; ++mb)
#pragma unroll
      for (int nb = 0; nb < NB; ++nb) {
        const int rg = row0 + wr * 128 + mb * 16 + fq * 4;
        const int cg = col0 + wc * WCW + nb * 16 + fr;
        const float bv = bias0[cg];
#pragma unroll
        for (int r = 0; r < 4; ++r)
          out_f[(size_t)(rg + r) * 1024 + cg] = acc[mb][nb][r] + bv;
      }
  }
}

// ---------------------------------------------------------------------------
// Output projection: 128x128, BK=64, 2 blocks/CU, single-barrier K-loop (r11).
__global__ __launch_bounds__(256, 2) void projg_k(const u16* __restrict__ A,
                                                  const u16* __restrict__ BT,
                                                  const float* __restrict__ bias,
                                                  float* __restrict__ out_f) {
  __shared__ __align__(16) u16 As[2][128 * 64];
  __shared__ __align__(16) u16 Bs[2][128 * 64];

  const int tid = threadIdx.x;
  const int w = tid >> 6, lane = tid & 63;
  const int wr = w >> 1, wc = w & 1;
  const int fr = lane & 15, fq = lane >> 4;
  const int d = fr & 7;

  const int bid = (int)blockIdx.x;
  const int xcd = bid & 7, c = bid >> 3;
  const int bx = xcd * 8 + (c >> 3);
  const int by = c & 7;
  const int row0 = bx * 128, col0 = by * 128;

  const int r0 = tid >> 3;
  const int cbg = (tid & 7) ^ (r0 & 7);
  const u16* Asrc = A + (size_t)(row0 + r0) * 1024 + cbg * 8;
  const u16* Bsrc = BT + (size_t)(col0 + r0) * 1024 + cbg * 8;

#define STAGEP(buf, t) do {                                                  \
    _Pragma("unroll")                                                        \
    for (int sw = 0; sw < 4; ++sw) {                                         \
      GLOAD_LDS16(Asrc + (size_t)sw * 32768 + (t) * 64,                      \
                  &As[buf][sw * 2048 + tid * 8]);                            \
      GLOAD_LDS16(Bsrc + (size_t)sw * 32768 + (t) * 64,                      \
                  &Bs[buf][sw * 2048 + tid * 8]);                            \
    }                                                                        \
  } while (0)

#define APOFF(mb, kk) ((wr * 64 + (mb) * 16 + fr) * 128 + (((((kk) << 2) | fq) ^ d) << 4))
#define BPOFF(nb, kk) ((wc * 64 + (nb) * 16 + fr) * 128 + (((((kk) << 2) | fq) ^ d) << 4))

  f32x4 acc[4][4] = {};

  STAGEP(0, 0);
  STAGEP(1, 1);
  asm volatile("s_waitcnt vmcnt(8)" ::: "memory");
  BARF();

#pragma unroll 1
  for (int g = 0; g < 16; ++g) {
    const int buf = g & 1;
    const char* Ac = (const char*)&As[buf][0];
    const char* Bc = (const char*)&Bs[buf][0];
    bf16x8 a[4][2], b[4][2];

#pragma unroll
    for (int mb = 0; mb < 4; ++mb) a[mb][0] = *(const bf16x8*)(Ac + APOFF(mb, 0));
#pragma unroll
    for (int nb = 0; nb < 4; ++nb) b[nb][0] = *(const bf16x8*)(Bc + BPOFF(nb, 0));
#pragma unroll
    for (int mb = 0; mb < 4; ++mb) a[mb][1] = *(const bf16x8*)(Ac + APOFF(mb, 1));
#pragma unroll
    for (int nb = 0; nb < 4; ++nb) b[nb][1] = *(const bf16x8*)(Bc + BPOFF(nb, 1));

    asm volatile("s_waitcnt lgkmcnt(8)" ::: "memory");
    __builtin_amdgcn_s_setprio(1);
#pragma unroll
    for (int mb = 0; mb < 4; ++mb)
#pragma unroll
      for (int nb = 0; nb < 4; ++nb)
        acc[mb][nb] = __builtin_amdgcn_mfma_f32_16x16x32_bf16(
            a[mb][0], b[nb][0], acc[mb][nb], 0, 0, 0);
    __builtin_amdgcn_s_setprio(0);

    asm volatile("s_waitcnt lgkmcnt(0)" ::: "memory");
    asm volatile("s_waitcnt vmcnt(0)" ::: "memory");
    BARF();
    if (g + 2 < 16) STAGEP(buf, g + 2);

    __builtin_amdgcn_s_setprio(1);
#pragma unroll
    for (int mb = 0; mb < 4; ++mb)
#pragma unroll
      for (int nb = 0; nb < 4; ++nb)
        acc[mb][nb] = __builtin_amdgcn_mfma_f32_16x16x32_bf16(
            a[mb][1], b[nb][1], acc[mb][nb], 0, 0, 0);
    __builtin_amdgcn_s_setprio(0);
  }
#undef STAGEP
#undef APOFF
#undef BPOFF

#pragma unroll
  for (int mb = 0; mb < 4; ++mb)
#pragma unroll
    for (int nb = 0; nb < 4; ++nb) {
      const int rg = row0 + wr * 64 + mb * 16 + fq * 4;
      const int cg = col0 + wc * 64 + nb * 16 + fr;
      const float bv = bias[cg];
#pragma unroll
      for (int r = 0; r < 4; ++r)
        out_f[(size_t)(rg + r) * 1024 + cg] = acc[mb][nb][r] + bv;
    }
}

// ---------------------------------------------------------------------------
// Fused-pair flash attention: each block owns i-tiles TA=pair and TB=15-pair.
// ONE j-loop to TB; each staged K/V tile feeds tile B always and tile A while
// jt <= TA (shared staging for the common prefix). Static-max softmax,
// XOR-swizzled LDS K/V, counted-vmcnt double-buffer.
__global__ __launch_bounds__(256, 4) void attn_k(const u16* __restrict__ Q,   // kproj (pre-scaled)
                                                 const u16* __restrict__ K,   // qproj
                                                 const u16* __restrict__ vT,  // [8][16][64][1024]
                                                 u16* __restrict__ O) {
  __shared__ __align__(16) u16 KsA[4096], KsB[4096], VsA[4096], VsB[4096];
  __shared__ __align__(16) u16 Plds[4][16][40];
  const int tid = threadIdx.x;
  const int w = tid >> 6, lane = tid & 63;
  const int fr = lane & 15, fq = lane >> 4, koff = fq * 8;

  const int n = blockIdx.x + 8 * (blockIdx.y + 16 * blockIdx.z);
  const int xcd = n & 7, rest = n >> 3;
  const int g = rest >> 3, pair = rest & 7;
  const int hb = xcd + 8 * g;
  const int h = hb & 15, b = hb >> 4;

  const size_t bstride = (size_t)1024 * 1024;
  const u16* Qb = Q + b * bstride + h * 64;
  const u16* Kg = K + b * bstride + h * 64;
  const u16* Vg = vT + ((size_t)(b * 16 + h) * 64) * 1024;

  const int srow = tid >> 3;
  const int scb = (tid & 7) ^ (srow & 7);
  const u16* KgT = Kg + (size_t)srow * 1024 + scb * 8;
  const u16* VgT = Vg + (size_t)srow * 1024 + scb * 8;

  const int vK0 = fr * 128 + ((fq ^ (fr & 7)) << 4);
  const int vK1 = vK0 ^ 64;
  const int pw = w * 1280 + fq * 320 + fr * 2;
  const int pr = w * 1280 + fr * 80 + fq * 16;

#define STAGE(KS, VS, jt) do {                                          \
    GLOAD_LDS16(KgT + (size_t)(jt) * 65536, &KS[tid * 8]);              \
    GLOAD_LDS16(KgT + (size_t)(jt) * 65536 + 32 * 1024, &KS[2048 + tid * 8]); \
    GLOAD_LDS16(VgT + (jt) * 64, &VS[tid * 8]);                         \
    GLOAD_LDS16(VgT + (jt) * 64 + 32 * 1024, &VS[2048 + tid * 8]);      \
  } while (0)

  const int TA = pair, TB = 15 - pair;      // TA < TB always (pair in 0..7)
  const int ibA = TA * 64 + w * 16, ibB = TB * 64 + w * 16;

  bf16x8 aqA0 = *reinterpret_cast<const bf16x8*>(&Qb[(size_t)(ibA + fr) * 1024 + koff]);
  bf16x8 aqA1 = *reinterpret_cast<const bf16x8*>(&Qb[(size_t)(ibA + fr) * 1024 + koff + 32]);
  bf16x8 aqB0 = *reinterpret_cast<const bf16x8*>(&Qb[(size_t)(ibB + fr) * 1024 + koff]);
  bf16x8 aqB1 = *reinterpret_cast<const bf16x8*>(&Qb[(size_t)(ibB + fr) * 1024 + koff + 32]);

  f32x4 oA[4] = {}, oB[4] = {};
  float lpA[4] = {0.f, 0.f, 0.f, 0.f}, lpB[4] = {0.f, 0.f, 0.f, 0.f};

  char* Pc = reinterpret_cast<char*>(&Plds[0][0][0]);

  // compute one 64x64 j-tile for one i-tile (accumulators passed by pointer;
  // all indices compile-time after unroll -> registers)
  auto compute = [&](const u16* KS, const u16* VS, bool diag,
                     bf16x8 aq0, bf16x8 aq1, f32x4* o, float* lp) {
    const char* Kc = reinterpret_cast<const char*>(KS);
    const char* Vc = reinterpret_cast<const char*>(VS);
    f32x4 s[4];
#pragma unroll
    for (int jc = 0; jc < 4; ++jc) {
      bf16x8 bk0 = *reinterpret_cast<const bf16x8*>(Kc + vK0 + jc * 2048);
      bf16x8 bk1 = *reinterpret_cast<const bf16x8*>(Kc + vK1 + jc * 2048);
      f32x4 z = {};
      z = __builtin_amdgcn_mfma_f32_16x16x32_bf16(aq0, bk0, z, 0, 0, 0);
      s[jc] = __builtin_amdgcn_mfma_f32_16x16x32_bf16(aq1, bk1, z, 0, 0, 0);
    }
    bf16x8 bv0[4], bv1[4];
#pragma unroll
    for (int dn = 0; dn < 4; ++dn) {
      bv0[dn] = *reinterpret_cast<const bf16x8*>(Vc + vK0 + dn * 2048);
      bv1[dn] = *reinterpret_cast<const bf16x8*>(Vc + vK1 + dn * 2048);
    }
    float p[4][4];
    if (diag) {
#pragma unroll
      for (int r = 0; r < 4; ++r) {
        const int il = w * 16 + fq * 4 + r;   // local row in 64-row tile
#pragma unroll
        for (int jc = 0; jc < 4; ++jc) {
          const int jl = jc * 16 + fr;        // local col in 64-col tile
          p[jc][r] = (jl <= il) ? __builtin_amdgcn_exp2f(s[jc][r]) : 0.f;
        }
      }
    } else {
#pragma unroll
      for (int r = 0; r < 4; ++r)
#pragma unroll
        for (int jc = 0; jc < 4; ++jc)
          p[jc][r] = __builtin_amdgcn_exp2f(s[jc][r]);
    }
#pragma unroll
    for (int r = 0; r < 4; ++r)
      lp[r] += (p[0][r] + p[1][r]) + (p[2][r] + p[3][r]);
#pragma unroll
    for (int jh = 0; jh < 2; ++jh) {
#pragma unroll
      for (int r = 0; r < 4; ++r)
#pragma unroll
        for (int j2 = 0; j2 < 2; ++j2)
          *reinterpret_cast<u16*>(Pc + pw + r * 80 + j2 * 32) = f2bf(p[jh * 2 + j2][r]);
      bf16x8 ap = *reinterpret_cast<const bf16x8*>(Pc + pr);
#pragma unroll
      for (int dn = 0; dn < 4; ++dn)
        o[dn] = __builtin_amdgcn_mfma_f32_16x16x32_bf16(ap, jh ? bv1[dn] : bv0[dn],
                                                        o[dn], 0, 0, 0);
    }
  };

  STAGE(KsA, VsA, 0);
  int t = 0;
  while (true) {
    {  // consume buffer A
      const bool more = t < TB;
      if (more) STAGE(KsB, VsB, t + 1);
      if (more) { asm volatile("s_waitcnt vmcnt(4)" ::: "memory"); }
      else      { asm volatile("s_waitcnt vmcnt(0)" ::: "memory"); }
      __builtin_amdgcn_s_barrier();
      compute(KsA, VsA, t == TB, aqB0, aqB1, oB, lpB);
      if (t <= TA) compute(KsA, VsA, t == TA, aqA0, aqA1, oA, lpA);
      __builtin_amdgcn_s_barrier();
      if (!more) break;
      ++t;
    }
    {  // consume buffer B
      const bool more = t < TB;
      if (more) STAGE(KsA, VsA, t + 1);
      if (more) { asm volatile("s_waitcnt vmcnt(4)" ::: "memory"); }
      else      { asm volatile("s_waitcnt vmcnt(0)" ::: "memory"); }
      __builtin_amdgcn_s_barrier();
      compute(KsB, VsB, t == TB, aqB0, aqB1, oB, lpB);
      if (t <= TA) compute(KsB, VsB, t == TA, aqA0, aqA1, oA, lpA);
      __builtin_amdgcn_s_barrier();
      if (!more) break;
      ++t;
    }
  }
#undef STAGE

  // epilogue: reduce partial sums across the 16-lane group, normalize, store
#pragma unroll
  for (int x = 1; x < 16; x <<= 1)
#pragma unroll
    for (int r = 0; r < 4; ++r) {
      lpA[r] += __shfl_xor(lpA[r], x);
      lpB[r] += __shfl_xor(lpB[r], x);
    }
#pragma unroll
  for (int r = 0; r < 4; ++r) {
    const float invA = 1.f / lpA[r];
    const float invB = 1.f / lpB[r];
    const int igA = ibA + fq * 4 + r;
    const int igB = ibB + fq * 4 + r;
#pragma unroll
    for (int dn = 0; dn < 4; ++dn) {
      O[((size_t)b * 1024 + igA) * 1024 + h * 64 + dn * 16 + fr] = f2bf(oA[dn][r] * invA);
      O[((size_t)b * 1024 + igB) * 1024 + h * 64 + dn * 16 + fr] = f2bf(oB[dn][r] * invB);
    }
  }
}

// ---------------------------------------------------------------------------
extern "C" void kernel_launch(void* const* d_in, const int* in_sizes, int n_in,
                              void* d_out, int out_size, void* d_ws, size_t ws_size,
                              hipStream_t stream) {
  const float* x  = (const float*)d_in[0];
  const float* Wk = (const float*)d_in[1];
  const float* bk = (const float*)d_in[2];
  const float* Wq = (const float*)d_in[3];
  const float* bq = (const float*)d_in[4];
  const float* Wv = (const float*)d_in[5];
  const float* bv = (const float*)d_in[6];
  const float* Wp = (const float*)d_in[7];
  const float* bp = (const float*)d_in[8];
  float* out = (float*)d_out;

  char* ws = (char*)d_ws;
  u16* xb   = (u16*)(ws);                           // 16 MB
  u16* WT   = (u16*)(ws + ((size_t)16 << 20));      //  8 MB  [Wk|Wq|Wv|Wp]^T
  u16* kbuf = (u16*)(ws + ((size_t)24 << 20));      // 16 MB (pre-scaled Q-role)
  u16* qbuf = (u16*)(ws + ((size_t)40 << 20));      // 16 MB
  u16* vT   = (u16*)(ws + ((size_t)56 << 20));      // 16 MB
  u16* aout = (u16*)(ws + ((size_t)72 << 20));      // 16 MB (ends at 88 MB)

  prep_k<<<5120, 256, 0, stream>>>(x, Wk, Wq, Wv, Wp, xb, WT);
  // fused QKV projection: N = 3072, BN=192 -> 512 blocks
  gemm8_k<0><<<512, 512, 0, stream>>>(xb, WT, bk, bq, bv,
                                      kbuf, qbuf, vT, nullptr);
  attn_k<<<dim3(8, 16, 8), 256, 0, stream>>>(kbuf, qbuf, vT, aout);
  // output projection: 128x128, 512 blocks = 2 blocks/CU, 1 round
  projg_k<<<512, 256, 0, stream>>>(aout, WT + (size_t)3 * 1024 * 1024, bp, out);
}

// Round 13
// 159.643 us; speedup vs baseline: 1.7992x; 1.7992x over previous
//
#include <hip/hip_runtime.h>

typedef unsigned short u16;
typedef unsigned int u32;
typedef __bf16 bf16x8 __attribute__((ext_vector_type(8)));
typedef float f32x4 __attribute__((ext_vector_type(4)));

// round-to-nearest-even f32 -> bf16 bits
__device__ __forceinline__ u16 f2bf(float f) {
  u32 u = __builtin_bit_cast(u32, f);
  u += 0x7fffu + ((u >> 16) & 1u);
  return (u16)(u >> 16);
}

#define GLOAD_LDS16(g, l) __builtin_amdgcn_global_load_lds( \
    (const __attribute__((address_space(1))) void*)(g),     \
    (__attribute__((address_space(3))) void*)(l), 16, 0, 0)

// scale folded into k-projection: C^-0.5 * log2(e)
#define SCK (0.03125f * 1.44269504088896f)

#define BARF() do { asm volatile("" ::: "memory"); \
                    __builtin_amdgcn_s_barrier();  \
                    asm volatile("" ::: "memory"); } while (0)

// ---------------------------------------------------------------------------
// Merged prep: blocks [0,4096): x f32->bf16; blocks [4096,5120): W transpose.
__global__ __launch_bounds__(256) void prep_k(const float* __restrict__ x,
                                              const float* __restrict__ W0,
                                              const float* __restrict__ W1,
                                              const float* __restrict__ W2,
                                              const float* __restrict__ W3,
                                              u16* __restrict__ xb,
                                              u16* __restrict__ WT) {
  __shared__ float tile[64][65];
  const int tid = threadIdx.x;
  if (blockIdx.x < 4096) {
    size_t i = (size_t)blockIdx.x * 256 + tid;
    const float4* p = reinterpret_cast<const float4*>(x) + i * 2;
    float4 a = p[0], b = p[1];
    u32 w0 = f2bf(a.x) | ((u32)f2bf(a.y) << 16);
    u32 w1 = f2bf(a.z) | ((u32)f2bf(a.w) << 16);
    u32 w2 = f2bf(b.x) | ((u32)f2bf(b.y) << 16);
    u32 w3 = f2bf(b.z) | ((u32)f2bf(b.w) << 16);
    uint4 o; o.x = w0; o.y = w1; o.z = w2; o.w = w3;
    *reinterpret_cast<uint4*>(xb + i * 8) = o;
    return;
  }
  const int bid2 = blockIdx.x - 4096;
  const int z = bid2 >> 8, kt = bid2 & 15, nt = (bid2 >> 4) & 15;
  const float* W = z == 0 ? W0 : z == 1 ? W1 : z == 2 ? W2 : W3;
  u16* dst = WT + (size_t)z * 1024 * 1024;
  const int k0 = kt * 64, n0 = nt * 64;
  const int rr = tid >> 4, c4 = (tid & 15) * 4;
#pragma unroll
  for (int p = 0; p < 4; ++p) {
    int r = rr + p * 16;
    float4 v = *reinterpret_cast<const float4*>(W + (size_t)(k0 + r) * 1024 + n0 + c4);
    tile[r][c4 + 0] = v.x; tile[r][c4 + 1] = v.y;
    tile[r][c4 + 2] = v.z; tile[r][c4 + 3] = v.w;
  }
  __syncthreads();
#pragma unroll
  for (int p = 0; p < 4; ++p) {
    int nl = rr + p * 16;
    u32 w0 = f2bf(tile[c4 + 0][nl]) | ((u32)f2bf(tile[c4 + 1][nl]) << 16);
    u32 w1 = f2bf(tile[c4 + 2][nl]) | ((u32)f2bf(tile[c4 + 3][nl]) << 16);
    uint2 o; o.x = w0; o.y = w1;
    *reinterpret_cast<uint2*>(dst + (size_t)(n0 + nl) * 1024 + k0 + c4) = o;
  }
}

// ---------------------------------------------------------------------------
// QKV bf16 GEMM, SINGLE-barrier K-loop (r11, unchanged).
template <int MODE>
__global__ __launch_bounds__(512, 2) void gemm8_k(
    const u16* __restrict__ A, const u16* __restrict__ BT,
    const float* __restrict__ bias0, const float* __restrict__ bias1,
    const float* __restrict__ bias2,
    u16* __restrict__ out_k, u16* __restrict__ out_q, u16* __restrict__ out_vT,
    float* __restrict__ out_f) {
  constexpr int BN = (MODE == 0) ? 192 : 128;
  constexpr int NB = BN / 64;        // col frags per wave: 3 or 2
  constexpr int LPT = 4 + NB;        // loads per thread per K-tile: 7 or 6
  constexpr int WCW = BN / 4;        // wave col width: 48 or 32
  constexpr int HALF = 8 + NB;       // reads per kk-half: 11 or 10

  __shared__ __align__(16) u16 As[2][256 * 64];
  __shared__ __align__(16) u16 Bs[2][BN * 64];

  const int tid = threadIdx.x;
  const int w = tid >> 6, lane = tid & 63;
  const int wr = w >> 2, wc = w & 3;
  const int fr = lane & 15, fq = lane >> 4;
  const int d = fr & 7;

  // XCD 2D region blocking (bijective; by varies fastest -> A-panel reuse)
  const int bid = (int)blockIdx.x;
  const int xcd = bid & 7, c = bid >> 3;
  int bx, by;
  if constexpr (MODE == 0) {
    bx = (xcd & 3) * 8 + (c >> 3);   // 4 bx-regions of 8
    by = (xcd >> 2) * 8 + (c & 7);   // 2 by-regions of 8
  } else {
    bx = xcd * 4 + (c >> 3);         // 8 bx-regions of 4
    by = c & 7;                      // all 8 by
  }
  const int row0 = bx * 256, col0 = by * BN;

  // staging source (inverse-swizzled per-lane global address)
  const int r0 = tid >> 3;
  const int cbg = (tid & 7) ^ (r0 & 7);
  const u16* Asrc = A + (size_t)(row0 + r0) * 1024 + cbg * 8;
  const u16* Bsrc = BT + (size_t)(col0 + r0) * 1024 + cbg * 8;

#define STAGE8(buf, t) do {                                                  \
    _Pragma("unroll")                                                        \
    for (int sw = 0; sw < 4; ++sw)                                           \
      GLOAD_LDS16(Asrc + (size_t)sw * 65536 + (t) * 64,                      \
                  &As[buf][sw * 4096 + tid * 8]);                            \
    _Pragma("unroll")                                                        \
    for (int sw = 0; sw < NB; ++sw)                                          \
      GLOAD_LDS16(Bsrc + (size_t)sw * 65536 + (t) * 64,                      \
                  &Bs[buf][sw * 4096 + tid * 8]);                            \
  } while (0)

  // swizzled frag byte offset: row*128 + (((kk*4+fq) ^ (row&7)) * 16)
#define AOFF(mb, kk) ((wr * 128 + (mb) * 16 + fr) * 128 + (((((kk) << 2) | fq) ^ d) << 4))
#define BOFF(nb, kk) ((wc * WCW + (nb) * 16 + fr) * 128 + (((((kk) << 2) | fq) ^ d) << 4))

  f32x4 acc[8][NB] = {};

  STAGE8(0, 0);
  STAGE8(1, 1);
  asm volatile("s_waitcnt vmcnt(%0)" :: "n"(LPT) : "memory");
  BARF();

#pragma unroll 1
  for (int g = 0; g < 16; ++g) {
    const int buf = g & 1;
    const char* Ac = (const char*)&As[buf][0];
    const char* Bc = (const char*)&Bs[buf][0];
    bf16x8 a[8][2], b[NB][2];

    // ---- issue ALL fragment reads: kk0 set first, then kk1 set ----
#pragma unroll
    for (int mb = 0; mb < 8; ++mb) a[mb][0] = *(const bf16x8*)(Ac + AOFF(mb, 0));
#pragma unroll
    for (int nb = 0; nb < NB; ++nb) b[nb][0] = *(const bf16x8*)(Bc + BOFF(nb, 0));
#pragma unroll
    for (int mb = 0; mb < 8; ++mb) a[mb][1] = *(const bf16x8*)(Ac + AOFF(mb, 1));
#pragma unroll
    for (int nb = 0; nb < NB; ++nb) b[nb][1] = *(const bf16x8*)(Bc + BOFF(nb, 1));

    // ---- kk0 MFMA burst; kk1 reads retire underneath ----
    asm volatile("s_waitcnt lgkmcnt(%0)" :: "n"(HALF) : "memory");
    __builtin_amdgcn_s_setprio(1);
#pragma unroll
    for (int mb = 0; mb < 8; ++mb)
#pragma unroll
      for (int nb = 0; nb < NB; ++nb)
        acc[mb][nb] = __builtin_amdgcn_mfma_f32_16x16x32_bf16(
            a[mb][0], b[nb][0], acc[mb][nb], 0, 0, 0);
    __builtin_amdgcn_s_setprio(0);

    // ---- ONE barrier merges both sync conditions ----
    asm volatile("s_waitcnt lgkmcnt(0)" ::: "memory");
    asm volatile("s_waitcnt vmcnt(0)" ::: "memory");
    BARF();
    if (g + 2 < 16) STAGE8(buf, g + 2);

    // ---- kk1 MFMA burst from registers (covers DMA issue) ----
    __builtin_amdgcn_s_setprio(1);
#pragma unroll
    for (int mb = 0; mb < 8; ++mb)
#pragma unroll
      for (int nb = 0; nb < NB; ++nb)
        acc[mb][nb] = __builtin_amdgcn_mfma_f32_16x16x32_bf16(
            a[mb][1], b[nb][1], acc[mb][nb], 0, 0, 0);
    __builtin_amdgcn_s_setprio(0);
  }
#undef STAGE8
#undef AOFF
#undef BOFF

  // ---- epilogue ----
  if constexpr (MODE == 0) {
#pragma unroll
    for (int mb = 0; mb < 8; ++mb) {
#pragma unroll
      for (int nb = 0; nb < NB; ++nb) {
        const int rg = row0 + wr * 128 + mb * 16 + fq * 4;
        const int cg = col0 + wc * WCW + nb * 16 + fr;
        const int which = cg >> 10;
        const int nloc = cg & 1023;
        const float bv = (which == 0 ? bias0 : which == 1 ? bias1 : bias2)[nloc];
        if (which == 0) {
#pragma unroll
          for (int r = 0; r < 4; ++r)
            out_k[(size_t)(rg + r) * 1024 + nloc] = f2bf((acc[mb][nb][r] + bv) * SCK);
        } else if (which == 1) {
#pragma unroll
          for (int r = 0; r < 4; ++r)
            out_q[(size_t)(rg + r) * 1024 + nloc] = f2bf(acc[mb][nb][r] + bv);
        } else {
          const int bb = rg >> 10, t = rg & 1023;
          const int hh = nloc >> 6, dl = nloc & 63;
          u32 w0 = f2bf(acc[mb][nb][0] + bv) | ((u32)f2bf(acc[mb][nb][1] + bv) << 16);
          u32 w1 = f2bf(acc[mb][nb][2] + bv) | ((u32)f2bf(acc[mb][nb][3] + bv) << 16);
          uint2 ov; ov.x = w0; ov.y = w1;
          *reinterpret_cast<uint2*>(out_vT + ((size_t)(bb * 16 + hh) * 64 + dl) * 1024 + t) = ov;
        }
      }
    }
  } else {
#pragma unroll
    for (int mb = 0; mb < 8; ++mb)
#pragma unroll
      for (int nb = 0; nb < NB; ++nb) {
        const int rg = row0 + wr * 128 + mb * 16 + fq * 4;
        const int cg = col0 + wc * WCW + nb * 16 + fr;
        const float bv = bias0[cg];
#pragma unroll
        for (int r = 0; r < 4; ++r)
          out_f[(size_t)(rg + r) * 1024 + cg] = acc[mb][nb][r] + bv;
      }
  }
}

// ---------------------------------------------------------------------------
// Output projection: 128x128, BK=64, 2 blocks/CU, single-barrier K-loop (r11).
__global__ __launch_bounds__(256, 2) void projg_k(const u16* __restrict__ A,
                                                  const u16* __restrict__ BT,
                                                  const float* __restrict__ bias,
                                                  float* __restrict__ out_f) {
  __shared__ __align__(16) u16 As[2][128 * 64];
  __shared__ __align__(16) u16 Bs[2][128 * 64];

  const int tid = threadIdx.x;
  const int w = tid >> 6, lane = tid & 63;
  const int wr = w >> 1, wc = w & 1;
  const int fr = lane & 15, fq = lane >> 4;
  const int d = fr & 7;

  const int bid = (int)blockIdx.x;
  const int xcd = bid & 7, c = bid >> 3;
  const int bx = xcd * 8 + (c >> 3);
  const int by = c & 7;
  const int row0 = bx * 128, col0 = by * 128;

  const int r0 = tid >> 3;
  const int cbg = (tid & 7) ^ (r0 & 7);
  const u16* Asrc = A + (size_t)(row0 + r0) * 1024 + cbg * 8;
  const u16* Bsrc = BT + (size_t)(col0 + r0) * 1024 + cbg * 8;

#define STAGEP(buf, t) do {                                                  \
    _Pragma("unroll")                                                        \
    for (int sw = 0; sw < 4; ++sw) {                                         \
      GLOAD_LDS16(Asrc + (size_t)sw * 32768 + (t) * 64,                      \
                  &As[buf][sw * 2048 + tid * 8]);                            \
      GLOAD_LDS16(Bsrc + (size_t)sw * 32768 + (t) * 64,                      \
                  &Bs[buf][sw * 2048 + tid * 8]);                            \
    }                                                                        \
  } while (0)

#define APOFF(mb, kk) ((wr * 64 + (mb) * 16 + fr) * 128 + (((((kk) << 2) | fq) ^ d) << 4))
#define BPOFF(nb, kk) ((wc * 64 + (nb) * 16 + fr) * 128 + (((((kk) << 2) | fq) ^ d) << 4))

  f32x4 acc[4][4] = {};

  STAGEP(0, 0);
  STAGEP(1, 1);
  asm volatile("s_waitcnt vmcnt(8)" ::: "memory");
  BARF();

#pragma unroll 1
  for (int g = 0; g < 16; ++g) {
    const int buf = g & 1;
    const char* Ac = (const char*)&As[buf][0];
    const char* Bc = (const char*)&Bs[buf][0];
    bf16x8 a[4][2], b[4][2];

#pragma unroll
    for (int mb = 0; mb < 4; ++mb) a[mb][0] = *(const bf16x8*)(Ac + APOFF(mb, 0));
#pragma unroll
    for (int nb = 0; nb < 4; ++nb) b[nb][0] = *(const bf16x8*)(Bc + BPOFF(nb, 0));
#pragma unroll
    for (int mb = 0; mb < 4; ++mb) a[mb][1] = *(const bf16x8*)(Ac + APOFF(mb, 1));
#pragma unroll
    for (int nb = 0; nb < 4; ++nb) b[nb][1] = *(const bf16x8*)(Bc + BPOFF(nb, 1));

    asm volatile("s_waitcnt lgkmcnt(8)" ::: "memory");
    __builtin_amdgcn_s_setprio(1);
#pragma unroll
    for (int mb = 0; mb < 4; ++mb)
#pragma unroll
      for (int nb = 0; nb < 4; ++nb)
        acc[mb][nb] = __builtin_amdgcn_mfma_f32_16x16x32_bf16(
            a[mb][0], b[nb][0], acc[mb][nb], 0, 0, 0);
    __builtin_amdgcn_s_setprio(0);

    asm volatile("s_waitcnt lgkmcnt(0)" ::: "memory");
    asm volatile("s_waitcnt vmcnt(0)" ::: "memory");
    BARF();
    if (g + 2 < 16) STAGEP(buf, g + 2);

    __builtin_amdgcn_s_setprio(1);
#pragma unroll
    for (int mb = 0; mb < 4; ++mb)
#pragma unroll
      for (int nb = 0; nb < 4; ++nb)
        acc[mb][nb] = __builtin_amdgcn_mfma_f32_16x16x32_bf16(
            a[mb][1], b[nb][1], acc[mb][nb], 0, 0, 0);
    __builtin_amdgcn_s_setprio(0);
  }
#undef STAGEP
#undef APOFF
#undef BPOFF

#pragma unroll
  for (int mb = 0; mb < 4; ++mb)
#pragma unroll
    for (int nb = 0; nb < 4; ++nb) {
      const int rg = row0 + wr * 64 + mb * 16 + fq * 4;
      const int cg = col0 + wc * 64 + nb * 16 + fr;
      const float bv = bias[cg];
#pragma unroll
      for (int r = 0; r < 4; ++r)
        out_f[(size_t)(rg + r) * 1024 + cg] = acc[mb][nb][r] + bv;
    }
}

// ---------------------------------------------------------------------------
// Fused-pair flash attention (scratch-spill-free retry).
// Each block owns i-tiles TA=pair, TB=15-pair; ONE j-loop to TB; each staged
// K/V tile feeds tile B always and tile A while jt <= TA. The compute body is
// a MACRO over named accumulator arrays (compile-time indices only) so SROA
// keeps everything in registers (rule #20: no pointer-passed accumulators).
__global__ __launch_bounds__(256, 4) void attn_k(const u16* __restrict__ Q,   // kproj (pre-scaled)
                                                 const u16* __restrict__ K,   // qproj
                                                 const u16* __restrict__ vT,  // [8][16][64][1024]
                                                 u16* __restrict__ O) {
  __shared__ __align__(16) u16 KsA[4096], KsB[4096], VsA[4096], VsB[4096];
  __shared__ __align__(16) u16 Plds[4][16][40];
  const int tid = threadIdx.x;
  const int w = tid >> 6, lane = tid & 63;
  const int fr = lane & 15, fq = lane >> 4, koff = fq * 8;

  const int n = blockIdx.x + 8 * (blockIdx.y + 16 * blockIdx.z);
  const int xcd = n & 7, rest = n >> 3;
  const int g = rest >> 3, pair = rest & 7;
  const int hb = xcd + 8 * g;
  const int h = hb & 15, b = hb >> 4;

  const size_t bstride = (size_t)1024 * 1024;
  const u16* Qb = Q + b * bstride + h * 64;
  const u16* Kg = K + b * bstride + h * 64;
  const u16* Vg = vT + ((size_t)(b * 16 + h) * 64) * 1024;

  const int srow = tid >> 3;
  const int scb = (tid & 7) ^ (srow & 7);
  const u16* KgT = Kg + (size_t)srow * 1024 + scb * 8;
  const u16* VgT = Vg + (size_t)srow * 1024 + scb * 8;

  const int vK0 = fr * 128 + ((fq ^ (fr & 7)) << 4);
  const int vK1 = vK0 ^ 64;
  const int pw = w * 1280 + fq * 320 + fr * 2;
  const int pr = w * 1280 + fr * 80 + fq * 16;
  char* Pc = reinterpret_cast<char*>(&Plds[0][0][0]);

#define STAGE(KS, VS, jt) do {                                          \
    GLOAD_LDS16(KgT + (size_t)(jt) * 65536, &KS[tid * 8]);              \
    GLOAD_LDS16(KgT + (size_t)(jt) * 65536 + 32 * 1024, &KS[2048 + tid * 8]); \
    GLOAD_LDS16(VgT + (jt) * 64, &VS[tid * 8]);                         \
    GLOAD_LDS16(VgT + (jt) * 64 + 32 * 1024, &VS[2048 + tid * 8]);      \
  } while (0)

// compute one 64x64 j-tile for one i-tile. oacc/lpacc are NAMED local arrays
// indexed only by unrolled (compile-time) indices -> stay in registers.
#define COMPUTE(KS, VS, diagc, aq0, aq1, oacc, lpacc) do {                    \
    const char* Kc_ = reinterpret_cast<const char*>(KS);                      \
    const char* Vc_ = reinterpret_cast<const char*>(VS);                      \
    f32x4 s_[4];                                                              \
    _Pragma("unroll")                                                         \
    for (int jc = 0; jc < 4; ++jc) {                                          \
      bf16x8 bk0_ = *reinterpret_cast<const bf16x8*>(Kc_ + vK0 + jc * 2048);  \
      bf16x8 bk1_ = *reinterpret_cast<const bf16x8*>(Kc_ + vK1 + jc * 2048);  \
      f32x4 z_ = {};                                                          \
      z_ = __builtin_amdgcn_mfma_f32_16x16x32_bf16(aq0, bk0_, z_, 0, 0, 0);   \
      s_[jc] = __builtin_amdgcn_mfma_f32_16x16x32_bf16(aq1, bk1_, z_, 0, 0, 0);\
    }                                                                         \
    float p_[4][4];                                                           \
    if (diagc) {                                                              \
      _Pragma("unroll")                                                       \
      for (int r = 0; r < 4; ++r) {                                           \
        const int il_ = w * 16 + fq * 4 + r;                                  \
        _Pragma("unroll")                                                     \
        for (int jc = 0; jc < 4; ++jc) {                                      \
          const int jl_ = jc * 16 + fr;                                       \
          p_[jc][r] = (jl_ <= il_) ? __builtin_amdgcn_exp2f(s_[jc][r]) : 0.f; \
        }                                                                     \
      }                                                                       \
    } else {                                                                  \
      _Pragma("unroll")                                                       \
      for (int r = 0; r < 4; ++r)                                             \
        _Pragma("unroll")                                                     \
        for (int jc = 0; jc < 4; ++jc)                                        \
          p_[jc][r] = __builtin_amdgcn_exp2f(s_[jc][r]);                      \
    }                                                                         \
    _Pragma("unroll")                                                         \
    for (int r = 0; r < 4; ++r)                                               \
      lpacc[r] += (p_[0][r] + p_[1][r]) + (p_[2][r] + p_[3][r]);              \
    _Pragma("unroll")                                                         \
    for (int jh = 0; jh < 2; ++jh) {                                          \
      _Pragma("unroll")                                                       \
      for (int r = 0; r < 4; ++r)                                             \
        _Pragma("unroll")                                                     \
        for (int j2 = 0; j2 < 2; ++j2)                                        \
          *reinterpret_cast<u16*>(Pc + pw + r * 80 + j2 * 32) =               \
              f2bf(p_[jh * 2 + j2][r]);                                       \
      bf16x8 ap_ = *reinterpret_cast<const bf16x8*>(Pc + pr);                 \
      _Pragma("unroll")                                                       \
      for (int dn = 0; dn < 4; ++dn) {                                        \
        bf16x8 bv_ = *reinterpret_cast<const bf16x8*>(                        \
            Vc_ + (jh ? vK1 : vK0) + dn * 2048);                              \
        oacc[dn] = __builtin_amdgcn_mfma_f32_16x16x32_bf16(ap_, bv_,          \
                                                           oacc[dn], 0, 0, 0);\
      }                                                                       \
    }                                                                         \
  } while (0)

  const int TA = pair, TB = 15 - pair;      // TA < TB always (pair in 0..7)
  const int ibA = TA * 64 + w * 16, ibB = TB * 64 + w * 16;

  bf16x8 aqA0 = *reinterpret_cast<const bf16x8*>(&Qb[(size_t)(ibA + fr) * 1024 + koff]);
  bf16x8 aqA1 = *reinterpret_cast<const bf16x8*>(&Qb[(size_t)(ibA + fr) * 1024 + koff + 32]);
  bf16x8 aqB0 = *reinterpret_cast<const bf16x8*>(&Qb[(size_t)(ibB + fr) * 1024 + koff]);
  bf16x8 aqB1 = *reinterpret_cast<const bf16x8*>(&Qb[(size_t)(ibB + fr) * 1024 + koff + 32]);

  f32x4 oA[4] = {}, oB[4] = {};
  float lpA[4] = {0.f, 0.f, 0.f, 0.f}, lpB[4] = {0.f, 0.f, 0.f, 0.f};

  STAGE(KsA, VsA, 0);
  int t = 0;
  while (true) {
    {  // consume buffer A
      const bool more = t < TB;
      if (more) STAGE(KsB, VsB, t + 1);
      if (more) { asm volatile("s_waitcnt vmcnt(4)" ::: "memory"); }
      else      { asm volatile("s_waitcnt vmcnt(0)" ::: "memory"); }
      __builtin_amdgcn_s_barrier();
      COMPUTE(KsA, VsA, (t == TB), aqB0, aqB1, oB, lpB);
      if (t <= TA) COMPUTE(KsA, VsA, (t == TA), aqA0, aqA1, oA, lpA);
      __builtin_amdgcn_s_barrier();
      if (!more) break;
      ++t;
    }
    {  // consume buffer B
      const bool more = t < TB;
      if (more) STAGE(KsA, VsA, t + 1);
      if (more) { asm volatile("s_waitcnt vmcnt(4)" ::: "memory"); }
      else      { asm volatile("s_waitcnt vmcnt(0)" ::: "memory"); }
      __builtin_amdgcn_s_barrier();
      COMPUTE(KsB, VsB, (t == TB), aqB0, aqB1, oB, lpB);
      if (t <= TA) COMPUTE(KsB, VsB, (t == TA), aqA0, aqA1, oA, lpA);
      __builtin_amdgcn_s_barrier();
      if (!more) break;
      ++t;
    }
  }
#undef STAGE
#undef COMPUTE

  // epilogue: reduce partial sums across the 16-lane group, normalize, store
#pragma unroll
  for (int x = 1; x < 16; x <<= 1)
#pragma unroll
    for (int r = 0; r < 4; ++r) {
      lpA[r] += __shfl_xor(lpA[r], x);
      lpB[r] += __shfl_xor(lpB[r], x);
    }
#pragma unroll
  for (int r = 0; r < 4; ++r) {
    const float invA = 1.f / lpA[r];
    const float invB = 1.f / lpB[r];
    const int igA = ibA + fq * 4 + r;
    const int igB = ibB + fq * 4 + r;
#pragma unroll
    for (int dn = 0; dn < 4; ++dn) {
      O[((size_t)b * 1024 + igA) * 1024 + h * 64 + dn * 16 + fr] = f2bf(oA[dn][r] * invA);
      O[((size_t)b * 1024 + igB) * 1024 + h * 64 + dn * 16 + fr] = f2bf(oB[dn][r] * invB);
    }
  }
}

// ---------------------------------------------------------------------------
extern "C" void kernel_launch(void* const* d_in, const int* in_sizes, int n_in,
                              void* d_out, int out_size, void* d_ws, size_t ws_size,
                              hipStream_t stream) {
  const float* x  = (const float*)d_in[0];
  const float* Wk = (const float*)d_in[1];
  const float* bk = (const float*)d_in[2];
  const float* Wq = (const float*)d_in[3];
  const float* bq = (const float*)d_in[4];
  const float* Wv = (const float*)d_in[5];
  const float* bv = (const float*)d_in[6];
  const float* Wp = (const float*)d_in[7];
  const float* bp = (const float*)d_in[8];
  float* out = (float*)d_out;

  char* ws = (char*)d_ws;
  u16* xb   = (u16*)(ws);                           // 16 MB
  u16* WT   = (u16*)(ws + ((size_t)16 << 20));      //  8 MB  [Wk|Wq|Wv|Wp]^T
  u16* kbuf = (u16*)(ws + ((size_t)24 << 20));      // 16 MB (pre-scaled Q-role)
  u16* qbuf = (u16*)(ws + ((size_t)40 << 20));      // 16 MB
  u16* vT   = (u16*)(ws + ((size_t)56 << 20));      // 16 MB
  u16* aout = (u16*)(ws + ((size_t)72 << 20));      // 16 MB (ends at 88 MB)

  prep_k<<<5120, 256, 0, stream>>>(x, Wk, Wq, Wv, Wp, xb, WT);
  // fused QKV projection: N = 3072, BN=192 -> 512 blocks
  gemm8_k<0><<<512, 512, 0, stream>>>(xb, WT, bk, bq, bv,
                                      kbuf, qbuf, vT, nullptr);
  attn_k<<<dim3(8, 16, 8), 256, 0, stream>>>(kbuf, qbuf, vT, aout);
  // output projection: 128x128, 512 blocks = 2 blocks/CU, 1 round
  projg_k<<<512, 256, 0, stream>>>(aout, WT + (size_t)3 * 1024 * 1024, bp, out);
}

// Round 14
// 135.609 us; speedup vs baseline: 2.1181x; 1.1772x over previous
//
#include <hip/hip_runtime.h>

typedef unsigned short u16;
typedef unsigned int u32;
typedef __bf16 bf16x8 __attribute__((ext_vector_type(8)));
typedef float f32x4 __attribute__((ext_vector_type(4)));

// round-to-nearest-even f32 -> bf16 bits
__device__ __forceinline__ u16 f2bf(float f) {
  u32 u = __builtin_bit_cast(u32, f);
  u += 0x7fffu + ((u >> 16) & 1u);
  return (u16)(u >> 16);
}

#define GLOAD_LDS16(g, l) __builtin_amdgcn_global_load_lds( \
    (const __attribute__((address_space(1))) void*)(g),     \
    (__attribute__((address_space(3))) void*)(l), 16, 0, 0)

// scale folded into k-projection: C^-0.5 * log2(e)
#define SCK (0.03125f * 1.44269504088896f)

#define BARF() do { asm volatile("" ::: "memory"); \
                    __builtin_amdgcn_s_barrier();  \
                    asm volatile("" ::: "memory"); } while (0)

// ---------------------------------------------------------------------------
// Merged prep: blocks [0,4096): x f32->bf16; blocks [4096,5120): W transpose.
__global__ __launch_bounds__(256) void prep_k(const float* __restrict__ x,
                                              const float* __restrict__ W0,
                                              const float* __restrict__ W1,
                                              const float* __restrict__ W2,
                                              const float* __restrict__ W3,
                                              u16* __restrict__ xb,
                                              u16* __restrict__ WT) {
  __shared__ float tile[64][65];
  const int tid = threadIdx.x;
  if (blockIdx.x < 4096) {
    size_t i = (size_t)blockIdx.x * 256 + tid;
    const float4* p = reinterpret_cast<const float4*>(x) + i * 2;
    float4 a = p[0], b = p[1];
    u32 w0 = f2bf(a.x) | ((u32)f2bf(a.y) << 16);
    u32 w1 = f2bf(a.z) | ((u32)f2bf(a.w) << 16);
    u32 w2 = f2bf(b.x) | ((u32)f2bf(b.y) << 16);
    u32 w3 = f2bf(b.z) | ((u32)f2bf(b.w) << 16);
    uint4 o; o.x = w0; o.y = w1; o.z = w2; o.w = w3;
    *reinterpret_cast<uint4*>(xb + i * 8) = o;
    return;
  }
  const int bid2 = blockIdx.x - 4096;
  const int z = bid2 >> 8, kt = bid2 & 15, nt = (bid2 >> 4) & 15;
  const float* W = z == 0 ? W0 : z == 1 ? W1 : z == 2 ? W2 : W3;
  u16* dst = WT + (size_t)z * 1024 * 1024;
  const int k0 = kt * 64, n0 = nt * 64;
  const int rr = tid >> 4, c4 = (tid & 15) * 4;
#pragma unroll
  for (int p = 0; p < 4; ++p) {
    int r = rr + p * 16;
    float4 v = *reinterpret_cast<const float4*>(W + (size_t)(k0 + r) * 1024 + n0 + c4);
    tile[r][c4 + 0] = v.x; tile[r][c4 + 1] = v.y;
    tile[r][c4 + 2] = v.z; tile[r][c4 + 3] = v.w;
  }
  __syncthreads();
#pragma unroll
  for (int p = 0; p < 4; ++p) {
    int nl = rr + p * 16;
    u32 w0 = f2bf(tile[c4 + 0][nl]) | ((u32)f2bf(tile[c4 + 1][nl]) << 16);
    u32 w1 = f2bf(tile[c4 + 2][nl]) | ((u32)f2bf(tile[c4 + 3][nl]) << 16);
    uint2 o; o.x = w0; o.y = w1;
    *reinterpret_cast<uint2*>(dst + (size_t)(n0 + nl) * 1024 + k0 + c4) = o;
  }
}

// ---------------------------------------------------------------------------
// QKV bf16 GEMM, SINGLE-barrier K-loop (r11, unchanged).
template <int MODE>
__global__ __launch_bounds__(512, 2) void gemm8_k(
    const u16* __restrict__ A, const u16* __restrict__ BT,
    const float* __restrict__ bias0, const float* __restrict__ bias1,
    const float* __restrict__ bias2,
    u16* __restrict__ out_k, u16* __restrict__ out_q, u16* __restrict__ out_vT,
    float* __restrict__ out_f) {
  constexpr int BN = (MODE == 0) ? 192 : 128;
  constexpr int NB = BN / 64;        // col frags per wave: 3 or 2
  constexpr int LPT = 4 + NB;        // loads per thread per K-tile: 7 or 6
  constexpr int WCW = BN / 4;        // wave col width: 48 or 32
  constexpr int HALF = 8 + NB;       // reads per kk-half: 11 or 10

  __shared__ __align__(16) u16 As[2][256 * 64];
  __shared__ __align__(16) u16 Bs[2][BN * 64];

  const int tid = threadIdx.x;
  const int w = tid >> 6, lane = tid & 63;
  const int wr = w >> 2, wc = w & 3;
  const int fr = lane & 15, fq = lane >> 4;
  const int d = fr & 7;

  // XCD 2D region blocking (bijective; by varies fastest -> A-panel reuse)
  const int bid = (int)blockIdx.x;
  const int xcd = bid & 7, c = bid >> 3;
  int bx, by;
  if constexpr (MODE == 0) {
    bx = (xcd & 3) * 8 + (c >> 3);   // 4 bx-regions of 8
    by = (xcd >> 2) * 8 + (c & 7);   // 2 by-regions of 8
  } else {
    bx = xcd * 4 + (c >> 3);         // 8 bx-regions of 4
    by = c & 7;                      // all 8 by
  }
  const int row0 = bx * 256, col0 = by * BN;

  // staging source (inverse-swizzled per-lane global address)
  const int r0 = tid >> 3;
  const int cbg = (tid & 7) ^ (r0 & 7);
  const u16* Asrc = A + (size_t)(row0 + r0) * 1024 + cbg * 8;
  const u16* Bsrc = BT + (size_t)(col0 + r0) * 1024 + cbg * 8;

#define STAGE8(buf, t) do {                                                  \
    _Pragma("unroll")                                                        \
    for (int sw = 0; sw < 4; ++sw)                                           \
      GLOAD_LDS16(Asrc + (size_t)sw * 65536 + (t) * 64,                      \
                  &As[buf][sw * 4096 + tid * 8]);                            \
    _Pragma("unroll")                                                        \
    for (int sw = 0; sw < NB; ++sw)                                          \
      GLOAD_LDS16(Bsrc + (size_t)sw * 65536 + (t) * 64,                      \
                  &Bs[buf][sw * 4096 + tid * 8]);                            \
  } while (0)

  // swizzled frag byte offset: row*128 + (((kk*4+fq) ^ (row&7)) * 16)
#define AOFF(mb, kk) ((wr * 128 + (mb) * 16 + fr) * 128 + (((((kk) << 2) | fq) ^ d) << 4))
#define BOFF(nb, kk) ((wc * WCW + (nb) * 16 + fr) * 128 + (((((kk) << 2) | fq) ^ d) << 4))

  f32x4 acc[8][NB] = {};

  STAGE8(0, 0);
  STAGE8(1, 1);
  asm volatile("s_waitcnt vmcnt(%0)" :: "n"(LPT) : "memory");
  BARF();

#pragma unroll 1
  for (int g = 0; g < 16; ++g) {
    const int buf = g & 1;
    const char* Ac = (const char*)&As[buf][0];
    const char* Bc = (const char*)&Bs[buf][0];
    bf16x8 a[8][2], b[NB][2];

    // ---- issue ALL fragment reads: kk0 set first, then kk1 set ----
#pragma unroll
    for (int mb = 0; mb < 8; ++mb) a[mb][0] = *(const bf16x8*)(Ac + AOFF(mb, 0));
#pragma unroll
    for (int nb = 0; nb < NB; ++nb) b[nb][0] = *(const bf16x8*)(Bc + BOFF(nb, 0));
#pragma unroll
    for (int mb = 0; mb < 8; ++mb) a[mb][1] = *(const bf16x8*)(Ac + AOFF(mb, 1));
#pragma unroll
    for (int nb = 0; nb < NB; ++nb) b[nb][1] = *(const bf16x8*)(Bc + BOFF(nb, 1));

    // ---- kk0 MFMA burst; kk1 reads retire underneath ----
    asm volatile("s_waitcnt lgkmcnt(%0)" :: "n"(HALF) : "memory");
    __builtin_amdgcn_s_setprio(1);
#pragma unroll
    for (int mb = 0; mb < 8; ++mb)
#pragma unroll
      for (int nb = 0; nb < NB; ++nb)
        acc[mb][nb] = __builtin_amdgcn_mfma_f32_16x16x32_bf16(
            a[mb][0], b[nb][0], acc[mb][nb], 0, 0, 0);
    __builtin_amdgcn_s_setprio(0);

    // ---- ONE barrier merges both sync conditions ----
    asm volatile("s_waitcnt lgkmcnt(0)" ::: "memory");
    asm volatile("s_waitcnt vmcnt(0)" ::: "memory");
    BARF();
    if (g + 2 < 16) STAGE8(buf, g + 2);

    // ---- kk1 MFMA burst from registers (covers DMA issue) ----
    __builtin_amdgcn_s_setprio(1);
#pragma unroll
    for (int mb = 0; mb < 8; ++mb)
#pragma unroll
      for (int nb = 0; nb < NB; ++nb)
        acc[mb][nb] = __builtin_amdgcn_mfma_f32_16x16x32_bf16(
            a[mb][1], b[nb][1], acc[mb][nb], 0, 0, 0);
    __builtin_amdgcn_s_setprio(0);
  }
#undef STAGE8
#undef AOFF
#undef BOFF

  // ---- epilogue ----
  if constexpr (MODE == 0) {
#pragma unroll
    for (int mb = 0; mb < 8; ++mb) {
#pragma unroll
      for (int nb = 0; nb < NB; ++nb) {
        const int rg = row0 + wr * 128 + mb * 16 + fq * 4;
        const int cg = col0 + wc * WCW + nb * 16 + fr;
        const int which = cg >> 10;
        const int nloc = cg & 1023;
        const float bv = (which == 0 ? bias0 : which == 1 ? bias1 : bias2)[nloc];
        if (which == 0) {
#pragma unroll
          for (int r = 0; r < 4; ++r)
            out_k[(size_t)(rg + r) * 1024 + nloc] = f2bf((acc[mb][nb][r] + bv) * SCK);
        } else if (which == 1) {
#pragma unroll
          for (int r = 0; r < 4; ++r)
            out_q[(size_t)(rg + r) * 1024 + nloc] = f2bf(acc[mb][nb][r] + bv);
        } else {
          const int bb = rg >> 10, t = rg & 1023;
          const int hh = nloc >> 6, dl = nloc & 63;
          u32 w0 = f2bf(acc[mb][nb][0] + bv) | ((u32)f2bf(acc[mb][nb][1] + bv) << 16);
          u32 w1 = f2bf(acc[mb][nb][2] + bv) | ((u32)f2bf(acc[mb][nb][3] + bv) << 16);
          uint2 ov; ov.x = w0; ov.y = w1;
          *reinterpret_cast<uint2*>(out_vT + ((size_t)(bb * 16 + hh) * 64 + dl) * 1024 + t) = ov;
        }
      }
    }
  } else {
#pragma unroll
    for (int mb = 0; mb < 8; ++mb)
#pragma unroll
      for (int nb = 0; nb < NB; ++nb) {
        const int rg = row0 + wr * 128 + mb * 16 + fq * 4;
        const int cg = col0 + wc * WCW + nb * 16 + fr;
        const float bv = bias0[cg];
#pragma unroll
        for (int r = 0; r < 4; ++r)
          out_f[(size_t)(rg + r) * 1024 + cg] = acc[mb][nb][r] + bv;
      }
  }
}

// ---------------------------------------------------------------------------
// Output projection: 128x128, BK=64, 2 blocks/CU, single-barrier K-loop (r11).
__global__ __launch_bounds__(256, 2) void projg_k(const u16* __restrict__ A,
                                                  const u16* __restrict__ BT,
                                                  const float* __restrict__ bias,
                                                  float* __restrict__ out_f) {
  __shared__ __align__(16) u16 As[2][128 * 64];
  __shared__ __align__(16) u16 Bs[2][128 * 64];

  const int tid = threadIdx.x;
  const int w = tid >> 6, lane = tid & 63;
  const int wr = w >> 1, wc = w & 1;
  const int fr = lane & 15, fq = lane >> 4;
  const int d = fr & 7;

  const int bid = (int)blockIdx.x;
  const int xcd = bid & 7, c = bid >> 3;
  const int bx = xcd * 8 + (c >> 3);
  const int by = c & 7;
  const int row0 = bx * 128, col0 = by * 128;

  const int r0 = tid >> 3;
  const int cbg = (tid & 7) ^ (r0 & 7);
  const u16* Asrc = A + (size_t)(row0 + r0) * 1024 + cbg * 8;
  const u16* Bsrc = BT + (size_t)(col0 + r0) * 1024 + cbg * 8;

#define STAGEP(buf, t) do {                                                  \
    _Pragma("unroll")                                                        \
    for (int sw = 0; sw < 4; ++sw) {                                         \
      GLOAD_LDS16(Asrc + (size_t)sw * 32768 + (t) * 64,                      \
                  &As[buf][sw * 2048 + tid * 8]);                            \
      GLOAD_LDS16(Bsrc + (size_t)sw * 32768 + (t) * 64,                      \
                  &Bs[buf][sw * 2048 + tid * 8]);                            \
    }                                                                        \
  } while (0)

#define APOFF(mb, kk) ((wr * 64 + (mb) * 16 + fr) * 128 + (((((kk) << 2) | fq) ^ d) << 4))
#define BPOFF(nb, kk) ((wc * 64 + (nb) * 16 + fr) * 128 + (((((kk) << 2) | fq) ^ d) << 4))

  f32x4 acc[4][4] = {};

  STAGEP(0, 0);
  STAGEP(1, 1);
  asm volatile("s_waitcnt vmcnt(8)" ::: "memory");
  BARF();

#pragma unroll 1
  for (int g = 0; g < 16; ++g) {
    const int buf = g & 1;
    const char* Ac = (const char*)&As[buf][0];
    const char* Bc = (const char*)&Bs[buf][0];
    bf16x8 a[4][2], b[4][2];

#pragma unroll
    for (int mb = 0; mb < 4; ++mb) a[mb][0] = *(const bf16x8*)(Ac + APOFF(mb, 0));
#pragma unroll
    for (int nb = 0; nb < 4; ++nb) b[nb][0] = *(const bf16x8*)(Bc + BPOFF(nb, 0));
#pragma unroll
    for (int mb = 0; mb < 4; ++mb) a[mb][1] = *(const bf16x8*)(Ac + APOFF(mb, 1));
#pragma unroll
    for (int nb = 0; nb < 4; ++nb) b[nb][1] = *(const bf16x8*)(Bc + BPOFF(nb, 1));

    asm volatile("s_waitcnt lgkmcnt(8)" ::: "memory");
    __builtin_amdgcn_s_setprio(1);
#pragma unroll
    for (int mb = 0; mb < 4; ++mb)
#pragma unroll
      for (int nb = 0; nb < 4; ++nb)
        acc[mb][nb] = __builtin_amdgcn_mfma_f32_16x16x32_bf16(
            a[mb][0], b[nb][0], acc[mb][nb], 0, 0, 0);
    __builtin_amdgcn_s_setprio(0);

    asm volatile("s_waitcnt lgkmcnt(0)" ::: "memory");
    asm volatile("s_waitcnt vmcnt(0)" ::: "memory");
    BARF();
    if (g + 2 < 16) STAGEP(buf, g + 2);

    __builtin_amdgcn_s_setprio(1);
#pragma unroll
    for (int mb = 0; mb < 4; ++mb)
#pragma unroll
      for (int nb = 0; nb < 4; ++nb)
        acc[mb][nb] = __builtin_amdgcn_mfma_f32_16x16x32_bf16(
            a[mb][1], b[nb][1], acc[mb][nb], 0, 0, 0);
    __builtin_amdgcn_s_setprio(0);
  }
#undef STAGEP
#undef APOFF
#undef BPOFF

#pragma unroll
  for (int mb = 0; mb < 4; ++mb)
#pragma unroll
    for (int nb = 0; nb < 4; ++nb) {
      const int rg = row0 + wr * 64 + mb * 16 + fq * 4;
      const int cg = col0 + wc * 64 + nb * 16 + fr;
      const float bv = bias[cg];
#pragma unroll
      for (int r = 0; r < 4; ++r)
        out_f[(size_t)(rg + r) * 1024 + cg] = acc[mb][nb][r] + bv;
    }
}

// ---------------------------------------------------------------------------
// Fused-pair flash attention. Single change vs r13: __launch_bounds__(256, 2)
// so the register allocator may use up to 256 VGPRs instead of spilling to
// scratch at the 8-wave/64-VGPR occupancy target (r13: WRITE_SIZE 175 MB of
// scratch traffic at VGPR=64). Expected ~110-130 VGPR -> 4 waves/SIMD, no
// spill. Algorithm unchanged: block owns i-tiles TA=pair, TB=15-pair; one
// j-loop; each staged K/V tile feeds B always, A while jt <= TA.
__global__ __launch_bounds__(256, 2) void attn_k(const u16* __restrict__ Q,   // kproj (pre-scaled)
                                                 const u16* __restrict__ K,   // qproj
                                                 const u16* __restrict__ vT,  // [8][16][64][1024]
                                                 u16* __restrict__ O) {
  __shared__ __align__(16) u16 KsA[4096], KsB[4096], VsA[4096], VsB[4096];
  __shared__ __align__(16) u16 Plds[4][16][40];
  const int tid = threadIdx.x;
  const int w = tid >> 6, lane = tid & 63;
  const int fr = lane & 15, fq = lane >> 4, koff = fq * 8;

  const int n = blockIdx.x + 8 * (blockIdx.y + 16 * blockIdx.z);
  const int xcd = n & 7, rest = n >> 3;
  const int g = rest >> 3, pair = rest & 7;
  const int hb = xcd + 8 * g;
  const int h = hb & 15, b = hb >> 4;

  const size_t bstride = (size_t)1024 * 1024;
  const u16* Qb = Q + b * bstride + h * 64;
  const u16* Kg = K + b * bstride + h * 64;
  const u16* Vg = vT + ((size_t)(b * 16 + h) * 64) * 1024;

  const int srow = tid >> 3;
  const int scb = (tid & 7) ^ (srow & 7);
  const u16* KgT = Kg + (size_t)srow * 1024 + scb * 8;
  const u16* VgT = Vg + (size_t)srow * 1024 + scb * 8;

  const int vK0 = fr * 128 + ((fq ^ (fr & 7)) << 4);
  const int vK1 = vK0 ^ 64;
  const int pw = w * 1280 + fq * 320 + fr * 2;
  const int pr = w * 1280 + fr * 80 + fq * 16;
  char* Pc = reinterpret_cast<char*>(&Plds[0][0][0]);

#define STAGE(KS, VS, jt) do {                                          \
    GLOAD_LDS16(KgT + (size_t)(jt) * 65536, &KS[tid * 8]);              \
    GLOAD_LDS16(KgT + (size_t)(jt) * 65536 + 32 * 1024, &KS[2048 + tid * 8]); \
    GLOAD_LDS16(VgT + (jt) * 64, &VS[tid * 8]);                         \
    GLOAD_LDS16(VgT + (jt) * 64 + 32 * 1024, &VS[2048 + tid * 8]);      \
  } while (0)

// compute one 64x64 j-tile for one i-tile. oacc/lpacc are NAMED local arrays
// indexed only by unrolled (compile-time) indices -> stay in registers.
#define COMPUTE(KS, VS, diagc, aq0, aq1, oacc, lpacc) do {                    \
    const char* Kc_ = reinterpret_cast<const char*>(KS);                      \
    const char* Vc_ = reinterpret_cast<const char*>(VS);                      \
    f32x4 s_[4];                                                              \
    _Pragma("unroll")                                                         \
    for (int jc = 0; jc < 4; ++jc) {                                          \
      bf16x8 bk0_ = *reinterpret_cast<const bf16x8*>(Kc_ + vK0 + jc * 2048);  \
      bf16x8 bk1_ = *reinterpret_cast<const bf16x8*>(Kc_ + vK1 + jc * 2048);  \
      f32x4 z_ = {};                                                          \
      z_ = __builtin_amdgcn_mfma_f32_16x16x32_bf16(aq0, bk0_, z_, 0, 0, 0);   \
      s_[jc] = __builtin_amdgcn_mfma_f32_16x16x32_bf16(aq1, bk1_, z_, 0, 0, 0);\
    }                                                                         \
    float p_[4][4];                                                           \
    if (diagc) {                                                              \
      _Pragma("unroll")                                                       \
      for (int r = 0; r < 4; ++r) {                                           \
        const int il_ = w * 16 + fq * 4 + r;                                  \
        _Pragma("unroll")                                                     \
        for (int jc = 0; jc < 4; ++jc) {                                      \
          const int jl_ = jc * 16 + fr;                                       \
          p_[jc][r] = (jl_ <= il_) ? __builtin_amdgcn_exp2f(s_[jc][r]) : 0.f; \
        }                                                                     \
      }                                                                       \
    } else {                                                                  \
      _Pragma("unroll")                                                       \
      for (int r = 0; r < 4; ++r)                                             \
        _Pragma("unroll")                                                     \
        for (int jc = 0; jc < 4; ++jc)                                        \
          p_[jc][r] = __builtin_amdgcn_exp2f(s_[jc][r]);                      \
    }                                                                         \
    _Pragma("unroll")                                                         \
    for (int r = 0; r < 4; ++r)                                               \
      lpacc[r] += (p_[0][r] + p_[1][r]) + (p_[2][r] + p_[3][r]);              \
    _Pragma("unroll")                                                         \
    for (int jh = 0; jh < 2; ++jh) {                                          \
      _Pragma("unroll")                                                       \
      for (int r = 0; r < 4; ++r)                                             \
        _Pragma("unroll")                                                     \
        for (int j2 = 0; j2 < 2; ++j2)                                        \
          *reinterpret_cast<u16*>(Pc + pw + r * 80 + j2 * 32) =               \
              f2bf(p_[jh * 2 + j2][r]);                                       \
      bf16x8 ap_ = *reinterpret_cast<const bf16x8*>(Pc + pr);                 \
      _Pragma("unroll")                                                       \
      for (int dn = 0; dn < 4; ++dn) {                                        \
        bf16x8 bv_ = *reinterpret_cast<const bf16x8*>(                        \
            Vc_ + (jh ? vK1 : vK0) + dn * 2048);                              \
        oacc[dn] = __builtin_amdgcn_mfma_f32_16x16x32_bf16(ap_, bv_,          \
                                                           oacc[dn], 0, 0, 0);\
      }                                                                       \
    }                                                                         \
  } while (0)

  const int TA = pair, TB = 15 - pair;      // TA < TB always (pair in 0..7)
  const int ibA = TA * 64 + w * 16, ibB = TB * 64 + w * 16;

  bf16x8 aqA0 = *reinterpret_cast<const bf16x8*>(&Qb[(size_t)(ibA + fr) * 1024 + koff]);
  bf16x8 aqA1 = *reinterpret_cast<const bf16x8*>(&Qb[(size_t)(ibA + fr) * 1024 + koff + 32]);
  bf16x8 aqB0 = *reinterpret_cast<const bf16x8*>(&Qb[(size_t)(ibB + fr) * 1024 + koff]);
  bf16x8 aqB1 = *reinterpret_cast<const bf16x8*>(&Qb[(size_t)(ibB + fr) * 1024 + koff + 32]);

  f32x4 oA[4] = {}, oB[4] = {};
  float lpA[4] = {0.f, 0.f, 0.f, 0.f}, lpB[4] = {0.f, 0.f, 0.f, 0.f};

  STAGE(KsA, VsA, 0);
  int t = 0;
  while (true) {
    {  // consume buffer A
      const bool more = t < TB;
      if (more) STAGE(KsB, VsB, t + 1);
      if (more) { asm volatile("s_waitcnt vmcnt(4)" ::: "memory"); }
      else      { asm volatile("s_waitcnt vmcnt(0)" ::: "memory"); }
      __builtin_amdgcn_s_barrier();
      COMPUTE(KsA, VsA, (t == TB), aqB0, aqB1, oB, lpB);
      if (t <= TA) COMPUTE(KsA, VsA, (t == TA), aqA0, aqA1, oA, lpA);
      __builtin_amdgcn_s_barrier();
      if (!more) break;
      ++t;
    }
    {  // consume buffer B
      const bool more = t < TB;
      if (more) STAGE(KsA, VsA, t + 1);
      if (more) { asm volatile("s_waitcnt vmcnt(4)" ::: "memory"); }
      else      { asm volatile("s_waitcnt vmcnt(0)" ::: "memory"); }
      __builtin_amdgcn_s_barrier();
      COMPUTE(KsB, VsB, (t == TB), aqB0, aqB1, oB, lpB);
      if (t <= TA) COMPUTE(KsB, VsB, (t == TA), aqA0, aqA1, oA, lpA);
      __builtin_amdgcn_s_barrier();
      if (!more) break;
      ++t;
    }
  }
#undef STAGE
#undef COMPUTE

  // epilogue: reduce partial sums across the 16-lane group, normalize, store
#pragma unroll
  for (int x = 1; x < 16; x <<= 1)
#pragma unroll
    for (int r = 0; r < 4; ++r) {
      lpA[r] += __shfl_xor(lpA[r], x);
      lpB[r] += __shfl_xor(lpB[r], x);
    }
#pragma unroll
  for (int r = 0; r < 4; ++r) {
    const float invA = 1.f / lpA[r];
    const float invB = 1.f / lpB[r];
    const int igA = ibA + fq * 4 + r;
    const int igB = ibB + fq * 4 + r;
#pragma unroll
    for (int dn = 0; dn < 4; ++dn) {
      O[((size_t)b * 1024 + igA) * 1024 + h * 64 + dn * 16 + fr] = f2bf(oA[dn][r] * invA);
      O[((size_t)b * 1024 + igB) * 1024 + h * 64 + dn * 16 + fr] = f2bf(oB[dn][r] * invB);
    }
  }
}

// ---------------------------------------------------------------------------
extern "C" void kernel_launch(void* const* d_in, const int* in_sizes, int n_in,
                              void* d_out, int out_size, void* d_ws, size_t ws_size,
                              hipStream_t stream) {
  const float* x  = (const float*)d_in[0];
  const float* Wk = (const float*)d_in[1];
  const float* bk = (const float*)d_in[2];
  const float* Wq = (const float*)d_in[3];
  const float* bq = (const float*)d_in[4];
  const float* Wv = (const float*)d_in[5];
  const float* bv = (const float*)d_in[6];
  const float* Wp = (const float*)d_in[7];
  const float* bp = (const float*)d_in[8];
  float* out = (float*)d_out;

  char* ws = (char*)d_ws;
  u16* xb   = (u16*)(ws);                           // 16 MB
  u16* WT   = (u16*)(ws + ((size_t)16 << 20));      //  8 MB  [Wk|Wq|Wv|Wp]^T
  u16* kbuf = (u16*)(ws + ((size_t)24 << 20));      // 16 MB (pre-scaled Q-role)
  u16* qbuf = (u16*)(ws + ((size_t)40 << 20));      // 16 MB
  u16* vT   = (u16*)(ws + ((size_t)56 << 20));      // 16 MB
  u16* aout = (u16*)(ws + ((size_t)72 << 20));      // 16 MB (ends at 88 MB)

  prep_k<<<5120, 256, 0, stream>>>(x, Wk, Wq, Wv, Wp, xb, WT);
  // fused QKV projection: N = 3072, BN=192 -> 512 blocks
  gemm8_k<0><<<512, 512, 0, stream>>>(xb, WT, bk, bq, bv,
                                      kbuf, qbuf, vT, nullptr);
  attn_k<<<dim3(8, 16, 8), 256, 0, stream>>>(kbuf, qbuf, vT, aout);
  // output projection: 128x128, 512 blocks = 2 blocks/CU, 1 round
  projg_k<<<512, 256, 0, stream>>>(aout, WT + (size_t)3 * 1024 * 1024, bp, out);
}

// Round 15
// 128.257 us; speedup vs baseline: 2.2395x; 1.0573x over previous
//
#include <hip/hip_runtime.h>

typedef unsigned short u16;
typedef unsigned int u32;
typedef __bf16 bf16x8 __attribute__((ext_vector_type(8)));
typedef float f32x4 __attribute__((ext_vector_type(4)));

// round-to-nearest-even f32 -> bf16 bits
__device__ __forceinline__ u16 f2bf(float f) {
  u32 u = __builtin_bit_cast(u32, f);
  u += 0x7fffu + ((u >> 16) & 1u);
  return (u16)(u >> 16);
}

#define GLOAD_LDS16(g, l) __builtin_amdgcn_global_load_lds( \
    (const __attribute__((address_space(1))) void*)(g),     \
    (__attribute__((address_space(3))) void*)(l), 16, 0, 0)

// scale folded into k-projection: C^-0.5 * log2(e)
#define SCK (0.03125f * 1.44269504088896f)

#define BARF() do { asm volatile("" ::: "memory"); \
                    __builtin_amdgcn_s_barrier();  \
                    asm volatile("" ::: "memory"); } while (0)

// ---------------------------------------------------------------------------
// Merged prep: blocks [0,4096): x f32->bf16; blocks [4096,5120): W transpose.
__global__ __launch_bounds__(256) void prep_k(const float* __restrict__ x,
                                              const float* __restrict__ W0,
                                              const float* __restrict__ W1,
                                              const float* __restrict__ W2,
                                              const float* __restrict__ W3,
                                              u16* __restrict__ xb,
                                              u16* __restrict__ WT) {
  __shared__ float tile[64][65];
  const int tid = threadIdx.x;
  if (blockIdx.x < 4096) {
    size_t i = (size_t)blockIdx.x * 256 + tid;
    const float4* p = reinterpret_cast<const float4*>(x) + i * 2;
    float4 a = p[0], b = p[1];
    u32 w0 = f2bf(a.x) | ((u32)f2bf(a.y) << 16);
    u32 w1 = f2bf(a.z) | ((u32)f2bf(a.w) << 16);
    u32 w2 = f2bf(b.x) | ((u32)f2bf(b.y) << 16);
    u32 w3 = f2bf(b.z) | ((u32)f2bf(b.w) << 16);
    uint4 o; o.x = w0; o.y = w1; o.z = w2; o.w = w3;
    *reinterpret_cast<uint4*>(xb + i * 8) = o;
    return;
  }
  const int bid2 = blockIdx.x - 4096;
  const int z = bid2 >> 8, kt = bid2 & 15, nt = (bid2 >> 4) & 15;
  const float* W = z == 0 ? W0 : z == 1 ? W1 : z == 2 ? W2 : W3;
  u16* dst = WT + (size_t)z * 1024 * 1024;
  const int k0 = kt * 64, n0 = nt * 64;
  const int rr = tid >> 4, c4 = (tid & 15) * 4;
#pragma unroll
  for (int p = 0; p < 4; ++p) {
    int r = rr + p * 16;
    float4 v = *reinterpret_cast<const float4*>(W + (size_t)(k0 + r) * 1024 + n0 + c4);
    tile[r][c4 + 0] = v.x; tile[r][c4 + 1] = v.y;
    tile[r][c4 + 2] = v.z; tile[r][c4 + 3] = v.w;
  }
  __syncthreads();
#pragma unroll
  for (int p = 0; p < 4; ++p) {
    int nl = rr + p * 16;
    u32 w0 = f2bf(tile[c4 + 0][nl]) | ((u32)f2bf(tile[c4 + 1][nl]) << 16);
    u32 w1 = f2bf(tile[c4 + 2][nl]) | ((u32)f2bf(tile[c4 + 3][nl]) << 16);
    uint2 o; o.x = w0; o.y = w1;
    *reinterpret_cast<uint2*>(dst + (size_t)(n0 + nl) * 1024 + k0 + c4) = o;
  }
}

// ---------------------------------------------------------------------------
// QKV bf16 GEMM, SINGLE-barrier K-loop.
// Per K-tile: [22 frag reads -> lgkm(11) -> 24 MFMA kk0 (kk1 retires under)
//  -> lgkm(0) -> vmcnt(0) (full-tile slack) -> barrier -> STAGE(g+2)
//  -> 24 MFMA kk1 from regs].
template <int MODE>
__global__ __launch_bounds__(512, 2) void gemm8_k(
    const u16* __restrict__ A, const u16* __restrict__ BT,
    const float* __restrict__ bias0, const float* __restrict__ bias1,
    const float* __restrict__ bias2,
    u16* __restrict__ out_k, u16* __restrict__ out_q, u16* __restrict__ out_vT,
    float* __restrict__ out_f) {
  constexpr int BN = (MODE == 0) ? 192 : 128;
  constexpr int NB = BN / 64;        // col frags per wave: 3 or 2
  constexpr int LPT = 4 + NB;        // loads per thread per K-tile: 7 or 6
  constexpr int WCW = BN / 4;        // wave col width: 48 or 32
  constexpr int HALF = 8 + NB;       // reads per kk-half: 11 or 10

  __shared__ __align__(16) u16 As[2][256 * 64];
  __shared__ __align__(16) u16 Bs[2][BN * 64];

  const int tid = threadIdx.x;
  const int w = tid >> 6, lane = tid & 63;
  const int wr = w >> 2, wc = w & 3;
  const int fr = lane & 15, fq = lane >> 4;
  const int d = fr & 7;

  // XCD 2D region blocking (bijective; by varies fastest -> A-panel reuse)
  const int bid = (int)blockIdx.x;
  const int xcd = bid & 7, c = bid >> 3;
  int bx, by;
  if constexpr (MODE == 0) {
    bx = (xcd & 3) * 8 + (c >> 3);   // 4 bx-regions of 8
    by = (xcd >> 2) * 8 + (c & 7);   // 2 by-regions of 8
  } else {
    bx = xcd * 4 + (c >> 3);         // 8 bx-regions of 4
    by = c & 7;                      // all 8 by
  }
  const int row0 = bx * 256, col0 = by * BN;

  // staging source (inverse-swizzled per-lane global address)
  const int r0 = tid >> 3;
  const int cbg = (tid & 7) ^ (r0 & 7);
  const u16* Asrc = A + (size_t)(row0 + r0) * 1024 + cbg * 8;
  const u16* Bsrc = BT + (size_t)(col0 + r0) * 1024 + cbg * 8;

#define STAGE8(buf, t) do {                                                  \
    _Pragma("unroll")                                                        \
    for (int sw = 0; sw < 4; ++sw)                                           \
      GLOAD_LDS16(Asrc + (size_t)sw * 65536 + (t) * 64,                      \
                  &As[buf][sw * 4096 + tid * 8]);                            \
    _Pragma("unroll")                                                        \
    for (int sw = 0; sw < NB; ++sw)                                          \
      GLOAD_LDS16(Bsrc + (size_t)sw * 65536 + (t) * 64,                      \
                  &Bs[buf][sw * 4096 + tid * 8]);                            \
  } while (0)

  // swizzled frag byte offset: row*128 + (((kk*4+fq) ^ (row&7)) * 16)
#define AOFF(mb, kk) ((wr * 128 + (mb) * 16 + fr) * 128 + (((((kk) << 2) | fq) ^ d) << 4))
#define BOFF(nb, kk) ((wc * WCW + (nb) * 16 + fr) * 128 + (((((kk) << 2) | fq) ^ d) << 4))

  f32x4 acc[8][NB] = {};

  STAGE8(0, 0);
  STAGE8(1, 1);
  asm volatile("s_waitcnt vmcnt(%0)" :: "n"(LPT) : "memory");
  BARF();

#pragma unroll 1
  for (int g = 0; g < 16; ++g) {
    const int buf = g & 1;
    const char* Ac = (const char*)&As[buf][0];
    const char* Bc = (const char*)&Bs[buf][0];
    bf16x8 a[8][2], b[NB][2];

    // ---- issue ALL fragment reads: kk0 set first, then kk1 set ----
#pragma unroll
    for (int mb = 0; mb < 8; ++mb) a[mb][0] = *(const bf16x8*)(Ac + AOFF(mb, 0));
#pragma unroll
    for (int nb = 0; nb < NB; ++nb) b[nb][0] = *(const bf16x8*)(Bc + BOFF(nb, 0));
#pragma unroll
    for (int mb = 0; mb < 8; ++mb) a[mb][1] = *(const bf16x8*)(Ac + AOFF(mb, 1));
#pragma unroll
    for (int nb = 0; nb < NB; ++nb) b[nb][1] = *(const bf16x8*)(Bc + BOFF(nb, 1));

    // ---- kk0 MFMA burst; kk1 reads retire underneath ----
    asm volatile("s_waitcnt lgkmcnt(%0)" :: "n"(HALF) : "memory");
    __builtin_amdgcn_s_setprio(1);
#pragma unroll
    for (int mb = 0; mb < 8; ++mb)
#pragma unroll
      for (int nb = 0; nb < NB; ++nb)
        acc[mb][nb] = __builtin_amdgcn_mfma_f32_16x16x32_bf16(
            a[mb][0], b[nb][0], acc[mb][nb], 0, 0, 0);
    __builtin_amdgcn_s_setprio(0);

    // ---- ONE barrier merges both sync conditions ----
    asm volatile("s_waitcnt lgkmcnt(0)" ::: "memory");
    asm volatile("s_waitcnt vmcnt(0)" ::: "memory");
    BARF();
    if (g + 2 < 16) STAGE8(buf, g + 2);

    // ---- kk1 MFMA burst from registers (covers DMA issue) ----
    __builtin_amdgcn_s_setprio(1);
#pragma unroll
    for (int mb = 0; mb < 8; ++mb)
#pragma unroll
      for (int nb = 0; nb < NB; ++nb)
        acc[mb][nb] = __builtin_amdgcn_mfma_f32_16x16x32_bf16(
            a[mb][1], b[nb][1], acc[mb][nb], 0, 0, 0);
    __builtin_amdgcn_s_setprio(0);
  }
#undef STAGE8
#undef AOFF
#undef BOFF

  // ---- epilogue ----
  if constexpr (MODE == 0) {
#pragma unroll
    for (int mb = 0; mb < 8; ++mb) {
#pragma unroll
      for (int nb = 0; nb < NB; ++nb) {
        const int rg = row0 + wr * 128 + mb * 16 + fq * 4;
        const int cg = col0 + wc * WCW + nb * 16 + fr;
        const int which = cg >> 10;
        const int nloc = cg & 1023;
        const float bv = (which == 0 ? bias0 : which == 1 ? bias1 : bias2)[nloc];
        if (which == 0) {
#pragma unroll
          for (int r = 0; r < 4; ++r)
            out_k[(size_t)(rg + r) * 1024 + nloc] = f2bf((acc[mb][nb][r] + bv) * SCK);
        } else if (which == 1) {
#pragma unroll
          for (int r = 0; r < 4; ++r)
            out_q[(size_t)(rg + r) * 1024 + nloc] = f2bf(acc[mb][nb][r] + bv);
        } else {
          const int bb = rg >> 10, t = rg & 1023;
          const int hh = nloc >> 6, dl = nloc & 63;
          u32 w0 = f2bf(acc[mb][nb][0] + bv) | ((u32)f2bf(acc[mb][nb][1] + bv) << 16);
          u32 w1 = f2bf(acc[mb][nb][2] + bv) | ((u32)f2bf(acc[mb][nb][3] + bv) << 16);
          uint2 ov; ov.x = w0; ov.y = w1;
          *reinterpret_cast<uint2*>(out_vT + ((size_t)(bb * 16 + hh) * 64 + dl) * 1024 + t) = ov;
        }
      }
    }
  } else {
#pragma unroll
    for (int mb = 0; mb < 8; ++mb)
#pragma unroll
      for (int nb = 0; nb < NB; ++nb) {
        const int rg = row0 + wr * 128 + mb * 16 + fq * 4;
        const int cg = col0 + wc * WCW + nb * 16 + fr;
        const float bv = bias0[cg];
#pragma unroll
        for (int r = 0; r < 4; ++r)
          out_f[(size_t)(rg + r) * 1024 + cg] = acc[mb][nb][r] + bv;
      }
  }
}

// ---------------------------------------------------------------------------
// Output projection: 128x128, BK=64, 2 blocks/CU, single-barrier K-loop.
__global__ __launch_bounds__(256, 2) void projg_k(const u16* __restrict__ A,
                                                  const u16* __restrict__ BT,
                                                  const float* __restrict__ bias,
                                                  float* __restrict__ out_f) {
  __shared__ __align__(16) u16 As[2][128 * 64];
  __shared__ __align__(16) u16 Bs[2][128 * 64];

  const int tid = threadIdx.x;
  const int w = tid >> 6, lane = tid & 63;
  const int wr = w >> 1, wc = w & 1;
  const int fr = lane & 15, fq = lane >> 4;
  const int d = fr & 7;

  const int bid = (int)blockIdx.x;
  const int xcd = bid & 7, c = bid >> 3;
  const int bx = xcd * 8 + (c >> 3);
  const int by = c & 7;
  const int row0 = bx * 128, col0 = by * 128;

  const int r0 = tid >> 3;
  const int cbg = (tid & 7) ^ (r0 & 7);
  const u16* Asrc = A + (size_t)(row0 + r0) * 1024 + cbg * 8;
  const u16* Bsrc = BT + (size_t)(col0 + r0) * 1024 + cbg * 8;

#define STAGEP(buf, t) do {                                                  \
    _Pragma("unroll")                                                        \
    for (int sw = 0; sw < 4; ++sw) {                                         \
      GLOAD_LDS16(Asrc + (size_t)sw * 32768 + (t) * 64,                      \
                  &As[buf][sw * 2048 + tid * 8]);                            \
      GLOAD_LDS16(Bsrc + (size_t)sw * 32768 + (t) * 64,                      \
                  &Bs[buf][sw * 2048 + tid * 8]);                            \
    }                                                                        \
  } while (0)

#define APOFF(mb, kk) ((wr * 64 + (mb) * 16 + fr) * 128 + (((((kk) << 2) | fq) ^ d) << 4))
#define BPOFF(nb, kk) ((wc * 64 + (nb) * 16 + fr) * 128 + (((((kk) << 2) | fq) ^ d) << 4))

  f32x4 acc[4][4] = {};

  STAGEP(0, 0);
  STAGEP(1, 1);
  asm volatile("s_waitcnt vmcnt(8)" ::: "memory");
  BARF();

#pragma unroll 1
  for (int g = 0; g < 16; ++g) {
    const int buf = g & 1;
    const char* Ac = (const char*)&As[buf][0];
    const char* Bc = (const char*)&Bs[buf][0];
    bf16x8 a[4][2], b[4][2];

#pragma unroll
    for (int mb = 0; mb < 4; ++mb) a[mb][0] = *(const bf16x8*)(Ac + APOFF(mb, 0));
#pragma unroll
    for (int nb = 0; nb < 4; ++nb) b[nb][0] = *(const bf16x8*)(Bc + BPOFF(nb, 0));
#pragma unroll
    for (int mb = 0; mb < 4; ++mb) a[mb][1] = *(const bf16x8*)(Ac + APOFF(mb, 1));
#pragma unroll
    for (int nb = 0; nb < 4; ++nb) b[nb][1] = *(const bf16x8*)(Bc + BPOFF(nb, 1));

    asm volatile("s_waitcnt lgkmcnt(8)" ::: "memory");
    __builtin_amdgcn_s_setprio(1);
#pragma unroll
    for (int mb = 0; mb < 4; ++mb)
#pragma unroll
      for (int nb = 0; nb < 4; ++nb)
        acc[mb][nb] = __builtin_amdgcn_mfma_f32_16x16x32_bf16(
            a[mb][0], b[nb][0], acc[mb][nb], 0, 0, 0);
    __builtin_amdgcn_s_setprio(0);

    asm volatile("s_waitcnt lgkmcnt(0)" ::: "memory");
    asm volatile("s_waitcnt vmcnt(0)" ::: "memory");
    BARF();
    if (g + 2 < 16) STAGEP(buf, g + 2);

    __builtin_amdgcn_s_setprio(1);
#pragma unroll
    for (int mb = 0; mb < 4; ++mb)
#pragma unroll
      for (int nb = 0; nb < 4; ++nb)
        acc[mb][nb] = __builtin_amdgcn_mfma_f32_16x16x32_bf16(
            a[mb][1], b[nb][1], acc[mb][nb], 0, 0, 0);
    __builtin_amdgcn_s_setprio(0);
  }
#undef STAGEP
#undef APOFF
#undef BPOFF

#pragma unroll
  for (int mb = 0; mb < 4; ++mb)
#pragma unroll
    for (int nb = 0; nb < 4; ++nb) {
      const int rg = row0 + wr * 64 + mb * 16 + fq * 4;
      const int cg = col0 + wc * 64 + nb * 16 + fr;
      const float bv = bias[cg];
#pragma unroll
      for (int r = 0; r < 4; ++r)
        out_f[(size_t)(rg + r) * 1024 + cg] = acc[mb][nb][r] + bv;
    }
}

// ---------------------------------------------------------------------------
// Flash-style causal attention, static-max softmax, LDS-staged K/V with
// counted-vmcnt double-buffer prefetch (r11 best version, reverted).
__global__ __launch_bounds__(256, 4) void attn_k(const u16* __restrict__ Q,   // kproj (pre-scaled)
                                                 const u16* __restrict__ K,   // qproj
                                                 const u16* __restrict__ vT,  // [8][16][64][1024]
                                                 u16* __restrict__ O) {
  __shared__ __align__(16) u16 KsA[4096], KsB[4096], VsA[4096], VsB[4096];
  __shared__ __align__(16) u16 Plds[4][16][40];
  const int tid = threadIdx.x;
  const int w = tid >> 6, lane = tid & 63;
  const int fr = lane & 15, fq = lane >> 4, koff = fq * 8;

  const int n = blockIdx.x + 8 * (blockIdx.y + 16 * blockIdx.z);
  const int xcd = n & 7, rest = n >> 3;
  const int g = rest >> 3, pair = rest & 7;
  const int hb = xcd + 8 * g;
  const int h = hb & 15, b = hb >> 4;

  const size_t bstride = (size_t)1024 * 1024;
  const u16* Qb = Q + b * bstride + h * 64;
  const u16* Kg = K + b * bstride + h * 64;
  const u16* Vg = vT + ((size_t)(b * 16 + h) * 64) * 1024;

  const int srow = tid >> 3;
  const int scb = (tid & 7) ^ (srow & 7);
  const u16* KgT = Kg + (size_t)srow * 1024 + scb * 8;
  const u16* VgT = Vg + (size_t)srow * 1024 + scb * 8;

  const int vK0 = fr * 128 + ((fq ^ (fr & 7)) << 4);
  const int vK1 = vK0 ^ 64;
  const int pw = w * 1280 + fq * 320 + fr * 2;
  const int pr = w * 1280 + fr * 80 + fq * 16;

#define STAGE(KS, VS, jt) do {                                          \
    GLOAD_LDS16(KgT + (size_t)(jt) * 65536, &KS[tid * 8]);              \
    GLOAD_LDS16(KgT + (size_t)(jt) * 65536 + 32 * 1024, &KS[2048 + tid * 8]); \
    GLOAD_LDS16(VgT + (jt) * 64, &VS[tid * 8]);                         \
    GLOAD_LDS16(VgT + (jt) * 64 + 32 * 1024, &VS[2048 + tid * 8]);      \
  } while (0)

#pragma unroll 1
  for (int ph = 0; ph < 2; ++ph) {
    const int T = ph ? (15 - pair) : pair;
    const int i0 = T * 64;
    const int ibase = i0 + w * 16;

    bf16x8 aq0 = *reinterpret_cast<const bf16x8*>(&Qb[(size_t)(ibase + fr) * 1024 + koff]);
    bf16x8 aq1 = *reinterpret_cast<const bf16x8*>(&Qb[(size_t)(ibase + fr) * 1024 + koff + 32]);

    f32x4 o[4] = {};
    float lp[4] = {0.f, 0.f, 0.f, 0.f};

    auto compute = [&](const u16* KS, const u16* VS, bool diag) {
      const char* Kc = reinterpret_cast<const char*>(KS);
      const char* Vc = reinterpret_cast<const char*>(VS);
      f32x4 s[4];
#pragma unroll
      for (int jc = 0; jc < 4; ++jc) {
        bf16x8 bk0 = *reinterpret_cast<const bf16x8*>(Kc + vK0 + jc * 2048);
        bf16x8 bk1 = *reinterpret_cast<const bf16x8*>(Kc + vK1 + jc * 2048);
        f32x4 z = {};
        z = __builtin_amdgcn_mfma_f32_16x16x32_bf16(aq0, bk0, z, 0, 0, 0);
        s[jc] = __builtin_amdgcn_mfma_f32_16x16x32_bf16(aq1, bk1, z, 0, 0, 0);
      }
      bf16x8 bv0[4], bv1[4];
#pragma unroll
      for (int dn = 0; dn < 4; ++dn) {
        bv0[dn] = *reinterpret_cast<const bf16x8*>(Vc + vK0 + dn * 2048);
        bv1[dn] = *reinterpret_cast<const bf16x8*>(Vc + vK1 + dn * 2048);
      }
      float p[4][4];
      if (diag) {
#pragma unroll
        for (int r = 0; r < 4; ++r) {
          const int il = w * 16 + fq * 4 + r;
#pragma unroll
          for (int jc = 0; jc < 4; ++jc) {
            const int jl = jc * 16 + fr;
            p[jc][r] = (jl <= il) ? __builtin_amdgcn_exp2f(s[jc][r]) : 0.f;
          }
        }
      } else {
#pragma unroll
        for (int r = 0; r < 4; ++r)
#pragma unroll
          for (int jc = 0; jc < 4; ++jc)
            p[jc][r] = __builtin_amdgcn_exp2f(s[jc][r]);
      }
#pragma unroll
      for (int r = 0; r < 4; ++r)
        lp[r] += (p[0][r] + p[1][r]) + (p[2][r] + p[3][r]);
      char* Pc = reinterpret_cast<char*>(&Plds[0][0][0]);
#pragma unroll
      for (int jh = 0; jh < 2; ++jh) {
#pragma unroll
        for (int r = 0; r < 4; ++r)
#pragma unroll
          for (int j2 = 0; j2 < 2; ++j2)
            *reinterpret_cast<u16*>(Pc + pw + r * 80 + j2 * 32) = f2bf(p[jh * 2 + j2][r]);
        bf16x8 ap = *reinterpret_cast<const bf16x8*>(Pc + pr);
#pragma unroll
        for (int dn = 0; dn < 4; ++dn)
          o[dn] = __builtin_amdgcn_mfma_f32_16x16x32_bf16(ap, jh ? bv1[dn] : bv0[dn],
                                                          o[dn], 0, 0, 0);
      }
    };

    STAGE(KsA, VsA, 0);
    int t = 0;
    while (true) {
      {
        const bool more = t < T;
        if (more) STAGE(KsB, VsB, t + 1);
        if (more) { asm volatile("s_waitcnt vmcnt(4)" ::: "memory"); }
        else      { asm volatile("s_waitcnt vmcnt(0)" ::: "memory"); }
        __builtin_amdgcn_s_barrier();
        compute(KsA, VsA, t == T);
        __builtin_amdgcn_s_barrier();
        if (!more) break;
        ++t;
      }
      {
        const bool more = t < T;
        if (more) STAGE(KsA, VsA, t + 1);
        if (more) { asm volatile("s_waitcnt vmcnt(4)" ::: "memory"); }
        else      { asm volatile("s_waitcnt vmcnt(0)" ::: "memory"); }
        __builtin_amdgcn_s_barrier();
        compute(KsB, VsB, t == T);
        __builtin_amdgcn_s_barrier();
        if (!more) break;
        ++t;
      }
    }

#pragma unroll
    for (int x = 1; x < 16; x <<= 1)
#pragma unroll
      for (int r = 0; r < 4; ++r) lp[r] += __shfl_xor(lp[r], x);
#pragma unroll
    for (int r = 0; r < 4; ++r) {
      const float inv = 1.f / lp[r];
      const int ig = ibase + fq * 4 + r;
#pragma unroll
      for (int dn = 0; dn < 4; ++dn)
        O[((size_t)b * 1024 + ig) * 1024 + h * 64 + dn * 16 + fr] = f2bf(o[dn][r] * inv);
    }
  }
#undef STAGE
}

// ---------------------------------------------------------------------------
extern "C" void kernel_launch(void* const* d_in, const int* in_sizes, int n_in,
                              void* d_out, int out_size, void* d_ws, size_t ws_size,
                              hipStream_t stream) {
  const float* x  = (const float*)d_in[0];
  const float* Wk = (const float*)d_in[1];
  const float* bk = (const float*)d_in[2];
  const float* Wq = (const float*)d_in[3];
  const float* bq = (const float*)d_in[4];
  const float* Wv = (const float*)d_in[5];
  const float* bv = (const float*)d_in[6];
  const float* Wp = (const float*)d_in[7];
  const float* bp = (const float*)d_in[8];
  float* out = (float*)d_out;

  char* ws = (char*)d_ws;
  u16* xb   = (u16*)(ws);                           // 16 MB
  u16* WT   = (u16*)(ws + ((size_t)16 << 20));      //  8 MB  [Wk|Wq|Wv|Wp]^T
  u16* kbuf = (u16*)(ws + ((size_t)24 << 20));      // 16 MB (pre-scaled Q-role)
  u16* qbuf = (u16*)(ws + ((size_t)40 << 20));      // 16 MB
  u16* vT   = (u16*)(ws + ((size_t)56 << 20));      // 16 MB
  u16* aout = (u16*)(ws + ((size_t)72 << 20));      // 16 MB (ends at 88 MB)

  prep_k<<<5120, 256, 0, stream>>>(x, Wk, Wq, Wv, Wp, xb, WT);
  // fused QKV projection: N = 3072, BN=192 -> 512 blocks
  gemm8_k<0><<<512, 512, 0, stream>>>(xb, WT, bk, bq, bv,
                                      kbuf, qbuf, vT, nullptr);
  attn_k<<<dim3(8, 16, 8), 256, 0, stream>>>(kbuf, qbuf, vT, aout);
  // output projection: 128x128, 512 blocks = 2 blocks/CU, 1 round
  projg_k<<<512, 256, 0, stream>>>(aout, WT + (size_t)3 * 1024 * 1024, bp, out);
}